// Round 3
// baseline (1795.980 us; speedup 1.0000x reference)
//
#include <hip/hip_runtime.h>

typedef __bf16 bf16;
typedef bf16 bf16x8 __attribute__((ext_vector_type(8)));
typedef bf16 bf16x4 __attribute__((ext_vector_type(4)));
typedef float floatx4 __attribute__((ext_vector_type(4)));

#define MFMA __builtin_amdgcn_mfma_f32_16x16x32_bf16

// ---------------- setup kernels ----------------

__global__ void hist_kernel(const int* __restrict__ ei, int* __restrict__ cnt, int E) {
  int e = blockIdx.x * blockDim.x + threadIdx.x;
  if (e < E) atomicAdd(&cnt[ei[E + e]], 1);
}

// batch is sorted: gcnt via binary search, no atomics (bhist was 235us of
// same-address atomic serialization)
__global__ void gcnt_kernel(const int* __restrict__ batch, int* __restrict__ gcnt,
                            int N, int B) {
  const int b = threadIdx.x;
  if (b >= B) return;
  auto lb = [&](int v) {
    int lo = 0, hi = N;
    while (lo < hi) {
      const int mid = (lo + hi) >> 1;
      if (batch[mid] < v) lo = mid + 1; else hi = mid;
    }
    return lo;
  };
  gcnt[b] = lb(b + 1) - lb(b);
}

// block-local exclusive scan (2048 elems/block) + block totals
__global__ void scan1_kernel(const int* __restrict__ cnt, int* __restrict__ rctr,
                             int* __restrict__ btot, int n) {
  __shared__ int sd[256];
  const int tid = threadIdx.x;
  const int i0 = blockIdx.x * 2048 + tid * 8;
  int v[8];
  int tot = 0;
#pragma unroll
  for (int j = 0; j < 8; ++j) {
    const int i = i0 + j;
    v[j] = (i < n) ? cnt[i] : 0;
    tot += v[j];
  }
  sd[tid] = tot;
  __syncthreads();
  for (int off = 1; off < 256; off <<= 1) {
    const int t = (tid >= off) ? sd[tid - off] : 0;
    __syncthreads();
    sd[tid] += t;
    __syncthreads();
  }
  int excl = sd[tid] - tot;
#pragma unroll
  for (int j = 0; j < 8; ++j) {
    const int i = i0 + j;
    if (i < n) rctr[i] = excl;
    excl += v[j];
  }
  if (tid == 255) btot[blockIdx.x] = sd[255];
}

__global__ void scan2_kernel(int* __restrict__ rctr, const int* __restrict__ btot, int n) {
  __shared__ int off_s;
  const int tid = threadIdx.x;
  if (blockIdx.x == 0) return;
  if (tid == 0) {
    int o = 0;
    for (int j = 0; j < (int)blockIdx.x; ++j) o += btot[j];
    off_s = o;
  }
  __syncthreads();
  const int off = off_s;
  const int i0 = blockIdx.x * 2048 + tid * 8;
#pragma unroll
  for (int j = 0; j < 8; ++j) {
    const int i = i0 + j;
    if (i < n) rctr[i] += off;
  }
}

__global__ void place_kernel(const int* __restrict__ ei, int* __restrict__ rctr,
                             int* __restrict__ esrow, int* __restrict__ escol, int E) {
  int e = blockIdx.x * blockDim.x + threadIdx.x;
  if (e >= E) return;
  const int r = ei[e];
  const int c = ei[E + e];
  const int p = atomicAdd(&rctr[c], 1);
  esrow[p] = r;
  escol[p] = c;
}

// transpose+split: src [L][K][H] fp32 -> dst [L][2][H][K] bf16 (hi, lo)
__global__ void wsplit_kernel(const float* __restrict__ src, bf16* __restrict__ dst,
                              int K, int HH) {
  const int l = blockIdx.y;
  const int gid = blockIdx.x * blockDim.x + threadIdx.x;
  if (gid >= K * HH) return;
  const int h = gid / K, k = gid - h * K;
  const float v = src[(size_t)l * K * HH + (size_t)k * HH + h];
  const bf16 hi = (bf16)v;
  const bf16 lo = (bf16)(v - (float)hi);
  bf16* d = dst + (size_t)l * 2 * K * HH;
  d[(size_t)h * K + k] = hi;
  d[(size_t)K * HH + (size_t)h * K + k] = lo;
}

__global__ void xsplit_kernel(const float* __restrict__ x, bf16* __restrict__ xhi,
                              bf16* __restrict__ xlo, int n4) {
  const int i = blockIdx.x * 256 + threadIdx.x;
  if (i >= n4) return;
  const float4 v = ((const float4*)x)[i];
  bf16x4 h, l;
  const float vv[4] = {v.x, v.y, v.z, v.w};
#pragma unroll
  for (int r = 0; r < 4; ++r) {
    h[r] = (bf16)vv[r];
    l[r] = (bf16)(vv[r] - (float)h[r]);
  }
  *(bf16x4*)&xhi[(size_t)i * 4] = h;
  *(bf16x4*)&xlo[(size_t)i * 4] = l;
}

// ---------------- edge MLP (MFMA, split-bf16) + fused segmented scatter ----
// GEMM1 B-fragments load DIRECT from global (fragment layout == row-major
// 16B chunks) — no LDS staging, no per-chunk barriers.
__global__ __launch_bounds__(256, 3)
void edge_mfma(const bf16* __restrict__ xhi, const bf16* __restrict__ xlo,
               const int* __restrict__ esrow, const int* __restrict__ escol,
               const bf16* __restrict__ w1t, const float* __restrict__ b1,
               const bf16* __restrict__ w2t, const float* __restrict__ b2,
               float* __restrict__ agg) {
  __shared__ __align__(16) bf16 H1[2][64 * 136];   // reused as Ms fp32 [128][65]
  __shared__ int srow_s[64], scol_s[64];

  const int tid = threadIdx.x;
  const int e0 = blockIdx.x * 64;
  const int wave = tid >> 6, lane = tid & 63, q = lane >> 4, lr = lane & 15;
  const int hbase = wave * 32;

  if (tid < 64) {
    srow_s[tid] = esrow[e0 + tid];
    scol_s[tid] = escol[e0 + tid];
  }
  __syncthreads();

  int rows[4];
#pragma unroll
  for (int nt = 0; nt < 4; ++nt) rows[nt] = srow_s[nt * 16 + lr];

  const floatx4 zz = {0.f, 0.f, 0.f, 0.f};
  floatx4 acc[2][4];
#pragma unroll
  for (int mt = 0; mt < 2; ++mt)
#pragma unroll
    for (int nt = 0; nt < 4; ++nt) acc[mt][nt] = zz;

  // ---- GEMM1: D1[h][e] = W1T x X, K=128, no barriers ----
#pragma unroll
  for (int kc = 0; kc < 4; ++kc) {
    bf16x8 ah[2], al[2], bh[4], bl[4];
#pragma unroll
    for (int mt = 0; mt < 2; ++mt) {
      const bf16* wp = w1t + (size_t)(hbase + mt * 16 + lr) * 128 + kc * 32 + q * 8;
      ah[mt] = *(const bf16x8*)wp;
      al[mt] = *(const bf16x8*)(wp + 16384);
    }
#pragma unroll
    for (int nt = 0; nt < 4; ++nt) {
      const size_t off = (size_t)rows[nt] * 128 + kc * 32 + q * 8;
      bh[nt] = *(const bf16x8*)(xhi + off);
      bl[nt] = *(const bf16x8*)(xlo + off);
    }
#pragma unroll
    for (int nt = 0; nt < 4; ++nt)
#pragma unroll
      for (int mt = 0; mt < 2; ++mt) {
        acc[mt][nt] = MFMA(ah[mt], bh[nt], acc[mt][nt], 0, 0, 0);
        acc[mt][nt] = MFMA(al[mt], bh[nt], acc[mt][nt], 0, 0, 0);
        acc[mt][nt] = MFMA(ah[mt], bl[nt], acc[mt][nt], 0, 0, 0);
      }
  }

  // ---- epilogue 1: bias+relu, split, write H1[e][h] ----
#pragma unroll
  for (int mt = 0; mt < 2; ++mt) {
    const int h0 = hbase + mt * 16 + q * 4;
    const float* bp = &b1[h0];
#pragma unroll
    for (int nt = 0; nt < 4; ++nt) {
      const int e = nt * 16 + lr;
      bf16x4 hh, ll;
#pragma unroll
      for (int r = 0; r < 4; ++r) {
        const float v = fmaxf(acc[mt][nt][r] + bp[r], 0.f);
        hh[r] = (bf16)v;
        ll[r] = (bf16)(v - (float)hh[r]);
      }
      *(bf16x4*)&H1[0][e * 136 + h0] = hh;
      *(bf16x4*)&H1[1][e * 136 + h0] = ll;
      acc[mt][nt] = zz;
    }
  }
  __syncthreads();

  // ---- GEMM2: D2[f][e] = W2T x H1 ----
#pragma unroll
  for (int ks = 0; ks < 4; ++ks) {
    bf16x8 ah[2], al[2], bh[4], bl[4];
#pragma unroll
    for (int mt = 0; mt < 2; ++mt) {
      const bf16* wp = w2t + (size_t)(hbase + mt * 16 + lr) * 128 + ks * 32 + q * 8;
      ah[mt] = *(const bf16x8*)wp;
      al[mt] = *(const bf16x8*)(wp + 16384);
    }
#pragma unroll
    for (int nt = 0; nt < 4; ++nt) {
      const bf16* hp = &H1[0][(nt * 16 + lr) * 136 + ks * 32 + q * 8];
      bh[nt] = *(const bf16x8*)hp;
      bl[nt] = *(const bf16x8*)(hp + 64 * 136);
    }
#pragma unroll
    for (int nt = 0; nt < 4; ++nt)
#pragma unroll
      for (int mt = 0; mt < 2; ++mt) {
        acc[mt][nt] = MFMA(ah[mt], bh[nt], acc[mt][nt], 0, 0, 0);
        acc[mt][nt] = MFMA(al[mt], bh[nt], acc[mt][nt], 0, 0, 0);
        acc[mt][nt] = MFMA(ah[mt], bl[nt], acc[mt][nt], 0, 0, 0);
      }
  }
  __syncthreads();  // all H1 reads done; Ms overlays H1

  // ---- epilogue 2: +b2 -> Ms[f][e] fp32 ----
  float* Ms = (float*)&H1[0][0];
#pragma unroll
  for (int mt = 0; mt < 2; ++mt) {
    const int f0 = hbase + mt * 16 + q * 4;
    const float* bp = &b2[f0];
#pragma unroll
    for (int nt = 0; nt < 4; ++nt) {
      const int e = nt * 16 + lr;
#pragma unroll
      for (int r = 0; r < 4; ++r) Ms[(f0 + r) * 65 + e] = acc[mt][nt][r] + bp[r];
    }
  }
  __syncthreads();

  // ---- segmented reduce along sorted cols, one atomic per run ----
  {
    const int f = tid & 127;
    const int es = (tid >> 7) * 32;
    int cur = scol_s[es];
    float s = 0.f;
    for (int e = es; e < es + 32; ++e) {
      const int col = scol_s[e];
      const float v = Ms[f * 65 + e];
      if (col != cur) {
        atomicAdd(&agg[(size_t)cur * 128 + f], s);
        s = 0.f;
        cur = col;
      }
      s += v;
    }
    atomicAdd(&agg[(size_t)cur * 128 + f], s);
  }
}

// ---------------- node MLP (MFMA, split-bf16), K=384, direct-load GEMM1 ----
__global__ __launch_bounds__(256, 3)
void node_mfma(bf16* xh, bf16* xl,                       // in AND out (disjoint rows)
               float* __restrict__ agg, const int* __restrict__ cnt,
               const float* __restrict__ u, const int* __restrict__ batch,
               const bf16* __restrict__ w1t, const float* __restrict__ b1,
               const bf16* __restrict__ w2t, const float* __restrict__ b2,
               float* __restrict__ xout, int N) {
  __shared__ __align__(16) bf16 H1[2][64 * 136];

  const int tid = threadIdx.x;
  const int n0 = blockIdx.x * 64;
  const int wave = tid >> 6, lane = tid & 63, q = lane >> 4, lr = lane & 15;
  const int hbase = wave * 32;

  int nn[4];
  float invc[4];
  int ub[4];
#pragma unroll
  for (int nt = 0; nt < 4; ++nt) {
    int n = n0 + nt * 16 + lr;
    if (n > N - 1) n = N - 1;
    nn[nt] = n;
    const int c_ = cnt[n];
    invc[nt] = 1.f / (float)(c_ > 1 ? c_ : 1);
    ub[nt] = batch[n];
  }

  const floatx4 zz = {0.f, 0.f, 0.f, 0.f};
  floatx4 acc[2][4];
#pragma unroll
  for (int mt = 0; mt < 2; ++mt)
#pragma unroll
    for (int nt = 0; nt < 4; ++nt) acc[mt][nt] = zz;

  // ---- GEMM1: K=384 (x | agg/cnt | u[batch]), no LDS staging ----
#pragma unroll
  for (int kc = 0; kc < 12; ++kc) {
    bf16x8 ah[2], al[2], bh[4], bl[4];
#pragma unroll
    for (int mt = 0; mt < 2; ++mt) {
      const bf16* wp = w1t + (size_t)(hbase + mt * 16 + lr) * 384 + kc * 32 + q * 8;
      ah[mt] = *(const bf16x8*)wp;
      al[mt] = *(const bf16x8*)(wp + 49152);
    }
#pragma unroll
    for (int nt = 0; nt < 4; ++nt) {
      if (kc < 4) {
        const size_t off = (size_t)nn[nt] * 128 + kc * 32 + q * 8;
        bh[nt] = *(const bf16x8*)(xh + off);
        bl[nt] = *(const bf16x8*)(xl + off);
      } else {
        float vv[8];
        if (kc < 8) {
          const float* s = agg + (size_t)nn[nt] * 128 + (kc - 4) * 32 + q * 8;
          const float4 a0 = *(const float4*)s;
          const float4 a1 = *(const float4*)(s + 4);
          const float inv = invc[nt];
          vv[0] = a0.x * inv; vv[1] = a0.y * inv; vv[2] = a0.z * inv; vv[3] = a0.w * inv;
          vv[4] = a1.x * inv; vv[5] = a1.y * inv; vv[6] = a1.z * inv; vv[7] = a1.w * inv;
        } else {
          const float* s = u + (size_t)ub[nt] * 128 + (kc - 8) * 32 + q * 8;
          const float4 a0 = *(const float4*)s;
          const float4 a1 = *(const float4*)(s + 4);
          vv[0] = a0.x; vv[1] = a0.y; vv[2] = a0.z; vv[3] = a0.w;
          vv[4] = a1.x; vv[5] = a1.y; vv[6] = a1.z; vv[7] = a1.w;
        }
#pragma unroll
        for (int r = 0; r < 8; ++r) {
          bh[nt][r] = (bf16)vv[r];
          bl[nt][r] = (bf16)(vv[r] - (float)bh[nt][r]);
        }
      }
    }
#pragma unroll
    for (int nt = 0; nt < 4; ++nt)
#pragma unroll
      for (int mt = 0; mt < 2; ++mt) {
        acc[mt][nt] = MFMA(ah[mt], bh[nt], acc[mt][nt], 0, 0, 0);
        acc[mt][nt] = MFMA(al[mt], bh[nt], acc[mt][nt], 0, 0, 0);
        acc[mt][nt] = MFMA(ah[mt], bl[nt], acc[mt][nt], 0, 0, 0);
      }
  }

  // ---- epilogue 1 ----
#pragma unroll
  for (int mt = 0; mt < 2; ++mt) {
    const int h0 = hbase + mt * 16 + q * 4;
    const float* bp = &b1[h0];
#pragma unroll
    for (int nt = 0; nt < 4; ++nt) {
      const int e = nt * 16 + lr;
      bf16x4 hh, ll;
#pragma unroll
      for (int r = 0; r < 4; ++r) {
        const float v = fmaxf(acc[mt][nt][r] + bp[r], 0.f);
        hh[r] = (bf16)v;
        ll[r] = (bf16)(v - (float)hh[r]);
      }
      *(bf16x4*)&H1[0][e * 136 + h0] = hh;
      *(bf16x4*)&H1[1][e * 136 + h0] = ll;
      acc[mt][nt] = zz;
    }
  }
  __syncthreads();   // also guarantees all agg reads (GEMM1) are complete

  // ---- GEMM2 ----
#pragma unroll
  for (int ks = 0; ks < 4; ++ks) {
    bf16x8 ah[2], al[2], bh[4], bl[4];
#pragma unroll
    for (int mt = 0; mt < 2; ++mt) {
      const bf16* wp = w2t + (size_t)(hbase + mt * 16 + lr) * 128 + ks * 32 + q * 8;
      ah[mt] = *(const bf16x8*)wp;
      al[mt] = *(const bf16x8*)(wp + 16384);
    }
#pragma unroll
    for (int nt = 0; nt < 4; ++nt) {
      const bf16* hp = &H1[0][(nt * 16 + lr) * 136 + ks * 32 + q * 8];
      bh[nt] = *(const bf16x8*)hp;
      bl[nt] = *(const bf16x8*)(hp + 64 * 136);
    }
#pragma unroll
    for (int nt = 0; nt < 4; ++nt)
#pragma unroll
      for (int mt = 0; mt < 2; ++mt) {
        acc[mt][nt] = MFMA(ah[mt], bh[nt], acc[mt][nt], 0, 0, 0);
        acc[mt][nt] = MFMA(al[mt], bh[nt], acc[mt][nt], 0, 0, 0);
        acc[mt][nt] = MFMA(ah[mt], bl[nt], acc[mt][nt], 0, 0, 0);
      }
  }

  // ---- epilogue 2: +b2, write xout fp32 + xh/xl bf16; zero agg rows for
  // next layer (this block exclusively owns rows n0..n0+63) ----
#pragma unroll
  for (int mt = 0; mt < 2; ++mt) {
    const int f0 = hbase + mt * 16 + q * 4;
    const float* bp = &b2[f0];
#pragma unroll
    for (int nt = 0; nt < 4; ++nt) {
      const int n = n0 + nt * 16 + lr;
      if (n < N) {
        float vv[4];
        bf16x4 hh, ll;
#pragma unroll
        for (int r = 0; r < 4; ++r) {
          vv[r] = acc[mt][nt][r] + bp[r];
          hh[r] = (bf16)vv[r];
          ll[r] = (bf16)(vv[r] - (float)hh[r]);
        }
        float4 o;
        o.x = vv[0]; o.y = vv[1]; o.z = vv[2]; o.w = vv[3];
        *(float4*)&xout[(size_t)n * 128 + f0] = o;
        *(bf16x4*)&xh[(size_t)n * 128 + f0] = hh;
        *(bf16x4*)&xl[(size_t)n * 128 + f0] = ll;
      }
    }
  }
  {
    const float4 z4 = {0.f, 0.f, 0.f, 0.f};
    for (int i = tid; i < 64 * 32; i += 256) {
      const int n = n0 + (i >> 5);
      if (n < N) ((float4*)agg)[(size_t)n * 32 + (i & 31)] = z4;
    }
  }
}

// ---------------- global scatter-sum (batch sorted) ----------------
__global__ __launch_bounds__(128)
void gsum_kernel(const float* __restrict__ xnew, const int* __restrict__ batch,
                 float* __restrict__ gx, int N) {
  const int tid = threadIdx.x;
  const int chunk = (N + gridDim.x - 1) / gridDim.x;
  const int n0 = blockIdx.x * chunk;
  int n1 = n0 + chunk;
  if (n1 > N) n1 = N;
  if (n0 >= N) return;
  int cur = batch[n0];
  float s = 0.f;
  for (int n = n0; n < n1; ++n) {
    const int b = batch[n];
    const float v = xnew[(size_t)n * 128 + tid];
    if (b != cur) {
      atomicAdd(&gx[(size_t)cur * 128 + tid], s);
      s = 0.f;
      cur = b;
    }
    s += v;
  }
  atomicAdd(&gx[(size_t)cur * 128 + tid], s);
}

// ---------------- global MLP (zeroes its gx row for next layer) ----------
__global__ __launch_bounds__(128)
void gmlp_kernel(const float* __restrict__ uin, float* __restrict__ gx,
                 const int* __restrict__ gcnt,
                 const float* __restrict__ gw1, const float* __restrict__ gb1,
                 const float* __restrict__ gw2, const float* __restrict__ gb2,
                 float* __restrict__ uout) {
  __shared__ float g[256];
  __shared__ float g1[128];
  const int b = blockIdx.x;
  const int t = threadIdx.x;
  const int c = gcnt[b];
  const float inv = 1.f / (float)(c > 1 ? c : 1);
  g[t] = uin[b * 128 + t];
  g[128 + t] = gx[b * 128 + t] * inv;
  gx[b * 128 + t] = 0.f;     // same thread read it above — no hazard
  __syncthreads();
  float acc = gb1[t];
#pragma unroll 8
  for (int k = 0; k < 256; ++k) acc = fmaf(g[k], gw1[k * 128 + t], acc);
  g1[t] = fmaxf(acc, 0.f);
  __syncthreads();
  float acc2 = gb2[t];
#pragma unroll 8
  for (int k = 0; k < 128; ++k) acc2 = fmaf(g1[k], gw2[k * 128 + t], acc2);
  uout[b * 128 + t] = acc2;
}

// ---------------- host ----------------
extern "C" void kernel_launch(void* const* d_in, const int* in_sizes, int n_in,
                              void* d_out, int out_size, void* d_ws, size_t ws_size,
                              hipStream_t stream) {
  constexpr int N = 50000, E = 600000, B = 64, F = 128, L = 4;

  const float* x0    = (const float*)d_in[0];
  const int*   ei    = (const int*)  d_in[1];
  const float* u0    = (const float*)d_in[2];
  const int*   batch = (const int*)  d_in[3];
  const float* n1w1  = (const float*)d_in[4];
  const float* n1b1  = (const float*)d_in[5];
  const float* n1w2  = (const float*)d_in[6];
  const float* n1b2  = (const float*)d_in[7];
  const float* n2w1  = (const float*)d_in[8];
  const float* n2b1  = (const float*)d_in[9];
  const float* n2w2  = (const float*)d_in[10];
  const float* n2b2  = (const float*)d_in[11];
  const float* gw1   = (const float*)d_in[12];
  const float* gb1   = (const float*)d_in[13];
  const float* gw2   = (const float*)d_in[14];
  const float* gb2   = (const float*)d_in[15];
  float* out = (float*)d_out;

  char* p = (char*)d_ws;
  auto carve = [&](size_t bytes) -> void* {
    void* q = (void*)p;
    p += (bytes + 255) & ~(size_t)255;
    return q;
  };
  float* xbuf  = (float*)carve((size_t)N * F * 4);
  float* agg   = (float*)carve((size_t)N * F * 4);
  float* ubuf  = (float*)carve((size_t)B * F * 4);
  float* gx    = (float*)carve((size_t)B * F * 4);
  int*   cnt   = (int*)carve((size_t)N * 4);
  int*   rctr  = (int*)carve((size_t)N * 4);
  int*   gcnt  = (int*)carve((size_t)B * 4);
  int*   btot  = (int*)carve(32 * 4);
  int*   esrow = (int*)carve((size_t)E * 4);
  int*   escol = (int*)carve((size_t)E * 4);
  bf16*  xhi   = (bf16*)carve((size_t)N * F * 2);
  bf16*  xlo   = (bf16*)carve((size_t)N * F * 2);
  bf16*  w1t_e = (bf16*)carve((size_t)L * 2 * 128 * 128 * 2);
  bf16*  w2t_e = (bf16*)carve((size_t)L * 2 * 128 * 128 * 2);
  bf16*  w1t_n = (bf16*)carve((size_t)L * 2 * 384 * 128 * 2);
  bf16*  w2t_n = (bf16*)carve((size_t)L * 2 * 128 * 128 * 2);

  constexpr int SCAN_BLOCKS = (N + 2047) / 2048;   // 25

  // setup
  hipMemsetAsync(cnt, 0, (size_t)N * 4, stream);
  hipMemsetAsync(agg, 0, (size_t)N * F * 4, stream);   // zeroed thereafter by node_mfma
  hipMemsetAsync(gx, 0, (size_t)B * F * 4, stream);    // zeroed thereafter by gmlp
  hist_kernel<<<(E + 255) / 256, 256, 0, stream>>>(ei, cnt, E);
  gcnt_kernel<<<1, 64, 0, stream>>>(batch, gcnt, N, B);
  scan1_kernel<<<SCAN_BLOCKS, 256, 0, stream>>>(cnt, rctr, btot, N);
  scan2_kernel<<<SCAN_BLOCKS, 256, 0, stream>>>(rctr, btot, N);
  place_kernel<<<(E + 255) / 256, 256, 0, stream>>>(ei, rctr, esrow, escol, E);
  wsplit_kernel<<<dim3(64, L), 256, 0, stream>>>(n1w1, w1t_e, 128, 128);
  wsplit_kernel<<<dim3(64, L), 256, 0, stream>>>(n1w2, w2t_e, 128, 128);
  wsplit_kernel<<<dim3(192, L), 256, 0, stream>>>(n2w1, w1t_n, 384, 128);
  wsplit_kernel<<<dim3(64, L), 256, 0, stream>>>(n2w2, w2t_n, 128, 128);
  xsplit_kernel<<<(N * F / 4 + 255) / 256, 256, 0, stream>>>(x0, xhi, xlo, N * F / 4);

  for (int l = 0; l < L; ++l) {
    float*       xout = (l == L - 1) ? out : xbuf;
    const float* uin  = l ? ubuf : u0;
    float*       uout = (l == L - 1) ? out + (size_t)N * F : ubuf;

    edge_mfma<<<E / 64, 256, 0, stream>>>(
        xhi, xlo, esrow, escol,
        w1t_e + (size_t)l * 32768, n1b1 + l * 128,
        w2t_e + (size_t)l * 32768, n1b2 + l * 128, agg);
    node_mfma<<<(N + 63) / 64, 256, 0, stream>>>(
        xhi, xlo, agg, cnt, uin, batch,
        w1t_n + (size_t)l * 98304, n2b1 + l * 128,
        w2t_n + (size_t)l * 32768, n2b2 + l * 128, xout, N);
    gsum_kernel<<<512, 128, 0, stream>>>(xout, batch, gx, N);
    gmlp_kernel<<<B, 128, 0, stream>>>(
        uin, gx, gcnt,
        gw1 + (size_t)l * 256 * 128, gb1 + l * 128,
        gw2 + (size_t)l * 128 * 128, gb2 + l * 128, uout);
  }
}

// Round 4
// 1098.530 us; speedup vs baseline: 1.6349x; 1.6349x over previous
//
#include <hip/hip_runtime.h>

typedef __bf16 bf16;
typedef bf16 bf16x8 __attribute__((ext_vector_type(8)));
typedef bf16 bf16x4 __attribute__((ext_vector_type(4)));
typedef float floatx4 __attribute__((ext_vector_type(4)));

#define MFMA __builtin_amdgcn_mfma_f32_16x16x32_bf16

// ---------------- setup kernels ----------------

__global__ void hist_kernel(const int* __restrict__ ei, int* __restrict__ cnt, int E) {
  int e = blockIdx.x * blockDim.x + threadIdx.x;
  if (e < E) atomicAdd(&cnt[ei[E + e]], 1);
}

// batch sorted: per-graph node counts via binary search (no atomics)
__global__ void gcnt_kernel(const int* __restrict__ batch, int* __restrict__ gcnt,
                            int N, int B) {
  const int b = threadIdx.x;
  if (b >= B) return;
  auto lb = [&](int v) {
    int lo = 0, hi = N;
    while (lo < hi) {
      const int mid = (lo + hi) >> 1;
      if (batch[mid] < v) lo = mid + 1; else hi = mid;
    }
    return lo;
  };
  gcnt[b] = lb(b + 1) - lb(b);
}

// block-local exclusive scan -> colptr (pristine) + rctr (working copy)
__global__ void scan1_kernel(const int* __restrict__ cnt, int* __restrict__ colptr,
                             int* __restrict__ rctr, int* __restrict__ btot, int n) {
  __shared__ int sd[256];
  const int tid = threadIdx.x;
  const int i0 = blockIdx.x * 2048 + tid * 8;
  int v[8];
  int tot = 0;
#pragma unroll
  for (int j = 0; j < 8; ++j) {
    const int i = i0 + j;
    v[j] = (i < n) ? cnt[i] : 0;
    tot += v[j];
  }
  sd[tid] = tot;
  __syncthreads();
  for (int off = 1; off < 256; off <<= 1) {
    const int t = (tid >= off) ? sd[tid - off] : 0;
    __syncthreads();
    sd[tid] += t;
    __syncthreads();
  }
  int excl = sd[tid] - tot;
#pragma unroll
  for (int j = 0; j < 8; ++j) {
    const int i = i0 + j;
    if (i < n) { colptr[i] = excl; rctr[i] = excl; }
    excl += v[j];
  }
  if (tid == 255) btot[blockIdx.x] = sd[255];
}

__global__ void scan2_kernel(int* __restrict__ colptr, int* __restrict__ rctr,
                             const int* __restrict__ btot, int n) {
  __shared__ int off_s;
  const int tid = threadIdx.x;
  if (blockIdx.x == 0) return;
  if (tid == 0) {
    int o = 0;
    for (int j = 0; j < (int)blockIdx.x; ++j) o += btot[j];
    off_s = o;
  }
  __syncthreads();
  const int off = off_s;
  const int i0 = blockIdx.x * 2048 + tid * 8;
#pragma unroll
  for (int j = 0; j < 8; ++j) {
    const int i = i0 + j;
    if (i < n) { colptr[i] += off; rctr[i] += off; }
  }
}

// counting-sort placement: esrow = source-node ids grouped by col
__global__ void place_kernel(const int* __restrict__ ei, int* __restrict__ rctr,
                             int* __restrict__ esrow, int E) {
  int e = blockIdx.x * blockDim.x + threadIdx.x;
  if (e >= E) return;
  const int r = ei[e];
  const int c = ei[E + e];
  const int p = atomicAdd(&rctr[c], 1);
  esrow[p] = r;
}

// transpose+split: src [L][Ksrc][H] fp32 (first K rows) -> dst [L][2][H][K] bf16
__global__ void wsplit_kernel(const float* __restrict__ src, bf16* __restrict__ dst,
                              int Ksrc, int K, int HH) {
  const int l = blockIdx.y;
  const int gid = blockIdx.x * blockDim.x + threadIdx.x;
  if (gid >= K * HH) return;
  const int h = gid / K, k = gid - h * K;
  const float v = src[(size_t)l * Ksrc * HH + (size_t)k * HH + h];
  const bf16 hi = (bf16)v;
  const bf16 lo = (bf16)(v - (float)hi);
  bf16* d = dst + (size_t)l * 2 * K * HH;
  d[(size_t)h * K + k] = hi;
  d[(size_t)K * HH + (size_t)h * K + k] = lo;
}

__global__ void xsplit_kernel(const float* __restrict__ x, bf16* __restrict__ xhi,
                              bf16* __restrict__ xlo, int n4) {
  const int i = blockIdx.x * 256 + threadIdx.x;
  if (i >= n4) return;
  const float4 v = ((const float4*)x)[i];
  bf16x4 h, l;
  const float vv[4] = {v.x, v.y, v.z, v.w};
#pragma unroll
  for (int r = 0; r < 4; ++r) {
    h[r] = (bf16)vv[r];
    l[r] = (bf16)(vv[r] - (float)h[r]);
  }
  *(bf16x4*)&xhi[(size_t)i * 4] = h;
  *(bf16x4*)&xlo[(size_t)i * 4] = l;
}

// ---------------- edge MLP per NODE (m depends only on x[row]!) ----------
// P = relu(X@W1+b1)@W2+b2  for all N nodes — 12x less GEMM than per-edge
__global__ __launch_bounds__(256, 3)
void pnode_mfma(const bf16* __restrict__ xh, const bf16* __restrict__ xl,
                const bf16* __restrict__ w1t, const float* __restrict__ b1,
                const bf16* __restrict__ w2t, const float* __restrict__ b2,
                bf16* __restrict__ P, int N) {
  __shared__ __align__(16) bf16 H1[2][64 * 136];

  const int tid = threadIdx.x;
  const int n0 = blockIdx.x * 64;
  const int wave = tid >> 6, lane = tid & 63, q = lane >> 4, lr = lane & 15;
  const int hbase = wave * 32;

  int nn[4];
#pragma unroll
  for (int nt = 0; nt < 4; ++nt) {
    int n = n0 + nt * 16 + lr;
    nn[nt] = (n > N - 1) ? (N - 1) : n;
  }

  const floatx4 zz = {0.f, 0.f, 0.f, 0.f};
  floatx4 acc[2][4];
#pragma unroll
  for (int mt = 0; mt < 2; ++mt)
#pragma unroll
    for (int nt = 0; nt < 4; ++nt) acc[mt][nt] = zz;

  // GEMM1: K=128, contiguous-row loads
#pragma unroll
  for (int kc = 0; kc < 4; ++kc) {
    bf16x8 ah[2], al[2], bh[4], bl[4];
#pragma unroll
    for (int mt = 0; mt < 2; ++mt) {
      const bf16* wp = w1t + (size_t)(hbase + mt * 16 + lr) * 128 + kc * 32 + q * 8;
      ah[mt] = *(const bf16x8*)wp;
      al[mt] = *(const bf16x8*)(wp + 16384);
    }
#pragma unroll
    for (int nt = 0; nt < 4; ++nt) {
      const size_t off = (size_t)nn[nt] * 128 + kc * 32 + q * 8;
      bh[nt] = *(const bf16x8*)(xh + off);
      bl[nt] = *(const bf16x8*)(xl + off);
    }
#pragma unroll
    for (int nt = 0; nt < 4; ++nt)
#pragma unroll
      for (int mt = 0; mt < 2; ++mt) {
        acc[mt][nt] = MFMA(ah[mt], bh[nt], acc[mt][nt], 0, 0, 0);
        acc[mt][nt] = MFMA(al[mt], bh[nt], acc[mt][nt], 0, 0, 0);
        acc[mt][nt] = MFMA(ah[mt], bl[nt], acc[mt][nt], 0, 0, 0);
      }
  }

  // epilogue 1: bias+relu, split -> H1[e][h]
#pragma unroll
  for (int mt = 0; mt < 2; ++mt) {
    const int h0 = hbase + mt * 16 + q * 4;
    const float* bp = &b1[h0];
#pragma unroll
    for (int nt = 0; nt < 4; ++nt) {
      const int e = nt * 16 + lr;
      bf16x4 hh, ll;
#pragma unroll
      for (int r = 0; r < 4; ++r) {
        const float v = fmaxf(acc[mt][nt][r] + bp[r], 0.f);
        hh[r] = (bf16)v;
        ll[r] = (bf16)(v - (float)hh[r]);
      }
      *(bf16x4*)&H1[0][e * 136 + h0] = hh;
      *(bf16x4*)&H1[1][e * 136 + h0] = ll;
      acc[mt][nt] = zz;
    }
  }
  __syncthreads();

  // GEMM2
#pragma unroll
  for (int ks = 0; ks < 4; ++ks) {
    bf16x8 ah[2], al[2], bh[4], bl[4];
#pragma unroll
    for (int mt = 0; mt < 2; ++mt) {
      const bf16* wp = w2t + (size_t)(hbase + mt * 16 + lr) * 128 + ks * 32 + q * 8;
      ah[mt] = *(const bf16x8*)wp;
      al[mt] = *(const bf16x8*)(wp + 16384);
    }
#pragma unroll
    for (int nt = 0; nt < 4; ++nt) {
      const bf16* hp = &H1[0][(nt * 16 + lr) * 136 + ks * 32 + q * 8];
      bh[nt] = *(const bf16x8*)hp;
      bl[nt] = *(const bf16x8*)(hp + 64 * 136);
    }
#pragma unroll
    for (int nt = 0; nt < 4; ++nt)
#pragma unroll
      for (int mt = 0; mt < 2; ++mt) {
        acc[mt][nt] = MFMA(ah[mt], bh[nt], acc[mt][nt], 0, 0, 0);
        acc[mt][nt] = MFMA(al[mt], bh[nt], acc[mt][nt], 0, 0, 0);
        acc[mt][nt] = MFMA(ah[mt], bl[nt], acc[mt][nt], 0, 0, 0);
      }
  }

  // epilogue 2: +b2, store P bf16
#pragma unroll
  for (int mt = 0; mt < 2; ++mt) {
    const int f0 = hbase + mt * 16 + q * 4;
    const float* bp = &b2[f0];
#pragma unroll
    for (int nt = 0; nt < 4; ++nt) {
      const int n = n0 + nt * 16 + lr;
      if (n < N) {
        bf16x4 o;
#pragma unroll
        for (int r = 0; r < 4; ++r) o[r] = (bf16)(acc[mt][nt][r] + bp[r]);
        *(bf16x4*)&P[(size_t)n * 128 + f0] = o;
      }
    }
  }
}

// ---------------- CSR mean-aggregate: agg[c] = mean P[row_e], pre-divided,
// written as bf16 hi/lo pair (node GEMM reads it like xh/xl) --------------
__global__ __launch_bounds__(256)
void agg_csr(const bf16* __restrict__ P, const int* __restrict__ colptr,
             const int* __restrict__ esrow,
             bf16* __restrict__ aggh, bf16* __restrict__ aggl, int N, int E) {
  const int tid = threadIdx.x;
  const int f = tid & 127;
  const int wp = tid >> 7;                 // wave-pair 0/1
  const int cbase = blockIdx.x * 8 + wp * 4;
  for (int ci = 0; ci < 4; ++ci) {
    const int c = cbase + ci;
    if (c >= N) return;
    const int beg = colptr[c];
    const int end = (c == N - 1) ? E : colptr[c + 1];
    float s0 = 0.f, s1 = 0.f;
    int e = beg;
    for (; e + 1 < end; e += 2) {          // 2-deep to halve latency chain
      const int r0 = esrow[e], r1 = esrow[e + 1];
      s0 += (float)P[(size_t)r0 * 128 + f];
      s1 += (float)P[(size_t)r1 * 128 + f];
    }
    if (e < end) s0 += (float)P[(size_t)esrow[e] * 128 + f];
    const int cc = end - beg;
    const float v = (s0 + s1) / (float)(cc > 1 ? cc : 1);
    const bf16 h = (bf16)v;
    aggh[(size_t)c * 128 + f] = h;
    aggl[(size_t)c * 128 + f] = (bf16)(v - (float)h);
  }
}

// ---------------- UW = u @ W1c + b1  (only 64 distinct u rows!) ----------
__global__ void uw_kernel(const float* __restrict__ u, const float* __restrict__ w1,
                          const float* __restrict__ b1, float* __restrict__ UW) {
  const int b = blockIdx.x, h = threadIdx.x;   // 64 blocks x 128 threads
  float s = b1[h];
#pragma unroll 8
  for (int k = 0; k < 128; ++k)
    s = fmaf(u[b * 128 + k], w1[(size_t)(256 + k) * 128 + h], s);
  UW[b * 128 + h] = s;
}

// ---------------- node MLP: K=256 (x | agg), acc init from UW[batch] -----
__global__ __launch_bounds__(256, 3)
void node_mfma(bf16* xh, bf16* xl,                        // in AND out (disjoint rows)
               const bf16* __restrict__ aggh, const bf16* __restrict__ aggl,
               const float* __restrict__ UW, const int* __restrict__ batch,
               const bf16* __restrict__ w1t, const bf16* __restrict__ w2t,
               const float* __restrict__ b2,
               float* __restrict__ xout, int N) {
  __shared__ __align__(16) bf16 H1[2][64 * 136];

  const int tid = threadIdx.x;
  const int n0 = blockIdx.x * 64;
  const int wave = tid >> 6, lane = tid & 63, q = lane >> 4, lr = lane & 15;
  const int hbase = wave * 32;

  int nn[4], ub[4];
#pragma unroll
  for (int nt = 0; nt < 4; ++nt) {
    int n = n0 + nt * 16 + lr;
    if (n > N - 1) n = N - 1;
    nn[nt] = n;
    ub[nt] = batch[n];
  }

  floatx4 acc[2][4];
#pragma unroll
  for (int mt = 0; mt < 2; ++mt)
#pragma unroll
    for (int nt = 0; nt < 4; ++nt)
      acc[mt][nt] = *(const floatx4*)&UW[(size_t)ub[nt] * 128 + hbase + mt * 16 + q * 4];

  // GEMM1: K=256 (x hi/lo | agg hi/lo), all contiguous bf16x8 loads
#pragma unroll
  for (int kc = 0; kc < 8; ++kc) {
    bf16x8 ah[2], al[2], bh[4], bl[4];
#pragma unroll
    for (int mt = 0; mt < 2; ++mt) {
      const bf16* wp = w1t + (size_t)(hbase + mt * 16 + lr) * 256 + kc * 32 + q * 8;
      ah[mt] = *(const bf16x8*)wp;
      al[mt] = *(const bf16x8*)(wp + 32768);
    }
#pragma unroll
    for (int nt = 0; nt < 4; ++nt) {
      if (kc < 4) {
        const size_t off = (size_t)nn[nt] * 128 + kc * 32 + q * 8;
        bh[nt] = *(const bf16x8*)(xh + off);
        bl[nt] = *(const bf16x8*)(xl + off);
      } else {
        const size_t off = (size_t)nn[nt] * 128 + (kc - 4) * 32 + q * 8;
        bh[nt] = *(const bf16x8*)(aggh + off);
        bl[nt] = *(const bf16x8*)(aggl + off);
      }
    }
#pragma unroll
    for (int nt = 0; nt < 4; ++nt)
#pragma unroll
      for (int mt = 0; mt < 2; ++mt) {
        acc[mt][nt] = MFMA(ah[mt], bh[nt], acc[mt][nt], 0, 0, 0);
        acc[mt][nt] = MFMA(al[mt], bh[nt], acc[mt][nt], 0, 0, 0);
        acc[mt][nt] = MFMA(ah[mt], bl[nt], acc[mt][nt], 0, 0, 0);
      }
  }

  // epilogue 1: relu (b1 folded into UW), split -> H1
  const floatx4 zz = {0.f, 0.f, 0.f, 0.f};
#pragma unroll
  for (int mt = 0; mt < 2; ++mt) {
    const int h0 = hbase + mt * 16 + q * 4;
#pragma unroll
    for (int nt = 0; nt < 4; ++nt) {
      const int e = nt * 16 + lr;
      bf16x4 hh, ll;
#pragma unroll
      for (int r = 0; r < 4; ++r) {
        const float v = fmaxf(acc[mt][nt][r], 0.f);
        hh[r] = (bf16)v;
        ll[r] = (bf16)(v - (float)hh[r]);
      }
      *(bf16x4*)&H1[0][e * 136 + h0] = hh;
      *(bf16x4*)&H1[1][e * 136 + h0] = ll;
      acc[mt][nt] = zz;
    }
  }
  __syncthreads();

  // GEMM2
#pragma unroll
  for (int ks = 0; ks < 4; ++ks) {
    bf16x8 ah[2], al[2], bh[4], bl[4];
#pragma unroll
    for (int mt = 0; mt < 2; ++mt) {
      const bf16* wp = w2t + (size_t)(hbase + mt * 16 + lr) * 128 + ks * 32 + q * 8;
      ah[mt] = *(const bf16x8*)wp;
      al[mt] = *(const bf16x8*)(wp + 16384);
    }
#pragma unroll
    for (int nt = 0; nt < 4; ++nt) {
      const bf16* hp = &H1[0][(nt * 16 + lr) * 136 + ks * 32 + q * 8];
      bh[nt] = *(const bf16x8*)hp;
      bl[nt] = *(const bf16x8*)(hp + 64 * 136);
    }
#pragma unroll
    for (int nt = 0; nt < 4; ++nt)
#pragma unroll
      for (int mt = 0; mt < 2; ++mt) {
        acc[mt][nt] = MFMA(ah[mt], bh[nt], acc[mt][nt], 0, 0, 0);
        acc[mt][nt] = MFMA(al[mt], bh[nt], acc[mt][nt], 0, 0, 0);
        acc[mt][nt] = MFMA(ah[mt], bl[nt], acc[mt][nt], 0, 0, 0);
      }
  }

  // epilogue 2: +b2 -> xout fp32 + refreshed xh/xl for next layer
#pragma unroll
  for (int mt = 0; mt < 2; ++mt) {
    const int f0 = hbase + mt * 16 + q * 4;
    const float* bp = &b2[f0];
#pragma unroll
    for (int nt = 0; nt < 4; ++nt) {
      const int n = n0 + nt * 16 + lr;
      if (n < N) {
        float vv[4];
        bf16x4 hh, ll;
#pragma unroll
        for (int r = 0; r < 4; ++r) {
          vv[r] = acc[mt][nt][r] + bp[r];
          hh[r] = (bf16)vv[r];
          ll[r] = (bf16)(vv[r] - (float)hh[r]);
        }
        float4 o;
        o.x = vv[0]; o.y = vv[1]; o.z = vv[2]; o.w = vv[3];
        *(float4*)&xout[(size_t)n * 128 + f0] = o;
        *(bf16x4*)&xh[(size_t)n * 128 + f0] = hh;
        *(bf16x4*)&xl[(size_t)n * 128 + f0] = ll;
      }
    }
  }
}

// ---------------- global scatter-sum (batch sorted) ----------------
__global__ __launch_bounds__(128)
void gsum_kernel(const float* __restrict__ xnew, const int* __restrict__ batch,
                 float* __restrict__ gx, int N) {
  const int tid = threadIdx.x;
  const int chunk = (N + gridDim.x - 1) / gridDim.x;
  const int n0 = blockIdx.x * chunk;
  int n1 = n0 + chunk;
  if (n1 > N) n1 = N;
  if (n0 >= N) return;
  int cur = batch[n0];
  float s = 0.f;
  for (int n = n0; n < n1; ++n) {
    const int b = batch[n];
    const float v = xnew[(size_t)n * 128 + tid];
    if (b != cur) {
      atomicAdd(&gx[(size_t)cur * 128 + tid], s);
      s = 0.f;
      cur = b;
    }
    s += v;
  }
  atomicAdd(&gx[(size_t)cur * 128 + tid], s);
}

// ---------------- global MLP (zeroes its gx row for next layer) ----------
__global__ __launch_bounds__(128)
void gmlp_kernel(const float* __restrict__ uin, float* __restrict__ gx,
                 const int* __restrict__ gcnt,
                 const float* __restrict__ gw1, const float* __restrict__ gb1,
                 const float* __restrict__ gw2, const float* __restrict__ gb2,
                 float* __restrict__ uout) {
  __shared__ float g[256];
  __shared__ float g1[128];
  const int b = blockIdx.x;
  const int t = threadIdx.x;
  const int c = gcnt[b];
  const float inv = 1.f / (float)(c > 1 ? c : 1);
  g[t] = uin[b * 128 + t];
  g[128 + t] = gx[b * 128 + t] * inv;
  gx[b * 128 + t] = 0.f;
  __syncthreads();
  float acc = gb1[t];
#pragma unroll 8
  for (int k = 0; k < 256; ++k) acc = fmaf(g[k], gw1[k * 128 + t], acc);
  g1[t] = fmaxf(acc, 0.f);
  __syncthreads();
  float acc2 = gb2[t];
#pragma unroll 8
  for (int k = 0; k < 128; ++k) acc2 = fmaf(g1[k], gw2[k * 128 + t], acc2);
  uout[b * 128 + t] = acc2;
}

// ---------------- host ----------------
extern "C" void kernel_launch(void* const* d_in, const int* in_sizes, int n_in,
                              void* d_out, int out_size, void* d_ws, size_t ws_size,
                              hipStream_t stream) {
  constexpr int N = 50000, E = 600000, B = 64, F = 128, L = 4;

  const float* x0    = (const float*)d_in[0];
  const int*   ei    = (const int*)  d_in[1];
  const float* u0    = (const float*)d_in[2];
  const int*   batch = (const int*)  d_in[3];
  const float* n1w1  = (const float*)d_in[4];
  const float* n1b1  = (const float*)d_in[5];
  const float* n1w2  = (const float*)d_in[6];
  const float* n1b2  = (const float*)d_in[7];
  const float* n2w1  = (const float*)d_in[8];
  const float* n2b1  = (const float*)d_in[9];
  const float* n2w2  = (const float*)d_in[10];
  const float* n2b2  = (const float*)d_in[11];
  const float* gw1   = (const float*)d_in[12];
  const float* gb1   = (const float*)d_in[13];
  const float* gw2   = (const float*)d_in[14];
  const float* gb2   = (const float*)d_in[15];
  float* out = (float*)d_out;

  char* p = (char*)d_ws;
  auto carve = [&](size_t bytes) -> void* {
    void* q = (void*)p;
    p += (bytes + 255) & ~(size_t)255;
    return q;
  };
  float* xbuf  = (float*)carve((size_t)N * F * 4);
  float* ubuf  = (float*)carve((size_t)B * F * 4);
  float* gx    = (float*)carve((size_t)B * F * 4);
  float* UW    = (float*)carve((size_t)B * F * 4);
  int*   cnt   = (int*)carve((size_t)N * 4);
  int*   colptr= (int*)carve((size_t)(N + 1) * 4);
  int*   rctr  = (int*)carve((size_t)N * 4);
  int*   gcnt  = (int*)carve((size_t)B * 4);
  int*   btot  = (int*)carve(32 * 4);
  int*   esrow = (int*)carve((size_t)E * 4);
  bf16*  xhi   = (bf16*)carve((size_t)N * F * 2);
  bf16*  xlo   = (bf16*)carve((size_t)N * F * 2);
  bf16*  P     = (bf16*)carve((size_t)N * F * 2);
  bf16*  aggh  = (bf16*)carve((size_t)N * F * 2);
  bf16*  aggl  = (bf16*)carve((size_t)N * F * 2);
  bf16*  w1t_e = (bf16*)carve((size_t)L * 2 * 128 * 128 * 2);
  bf16*  w2t_e = (bf16*)carve((size_t)L * 2 * 128 * 128 * 2);
  bf16*  w1t_n = (bf16*)carve((size_t)L * 2 * 256 * 128 * 2);
  bf16*  w2t_n = (bf16*)carve((size_t)L * 2 * 128 * 128 * 2);

  constexpr int SCAN_BLOCKS = (N + 2047) / 2048;   // 25

  // setup
  hipMemsetAsync(cnt, 0, (size_t)N * 4, stream);
  hipMemsetAsync(gx, 0, (size_t)B * F * 4, stream);   // re-zeroed by gmlp
  hist_kernel<<<(E + 255) / 256, 256, 0, stream>>>(ei, cnt, E);
  gcnt_kernel<<<1, 64, 0, stream>>>(batch, gcnt, N, B);
  scan1_kernel<<<SCAN_BLOCKS, 256, 0, stream>>>(cnt, colptr, rctr, btot, N);
  scan2_kernel<<<SCAN_BLOCKS, 256, 0, stream>>>(colptr, rctr, btot, N);
  place_kernel<<<(E + 255) / 256, 256, 0, stream>>>(ei, rctr, esrow, E);
  wsplit_kernel<<<dim3(64, L), 256, 0, stream>>>(n1w1, w1t_e, 128, 128, 128);
  wsplit_kernel<<<dim3(64, L), 256, 0, stream>>>(n1w2, w2t_e, 128, 128, 128);
  wsplit_kernel<<<dim3(128, L), 256, 0, stream>>>(n2w1, w1t_n, 384, 256, 128);
  wsplit_kernel<<<dim3(64, L), 256, 0, stream>>>(n2w2, w2t_n, 128, 128, 128);
  xsplit_kernel<<<(N * F / 4 + 255) / 256, 256, 0, stream>>>(x0, xhi, xlo, N * F / 4);

  const int NB = (N + 63) / 64;
  for (int l = 0; l < L; ++l) {
    float*       xout = (l == L - 1) ? out : xbuf;
    const float* uin  = l ? ubuf : u0;
    float*       uout = (l == L - 1) ? out + (size_t)N * F : ubuf;

    pnode_mfma<<<NB, 256, 0, stream>>>(
        xhi, xlo,
        w1t_e + (size_t)l * 32768, n1b1 + l * 128,
        w2t_e + (size_t)l * 32768, n1b2 + l * 128, P, N);
    agg_csr<<<(N + 7) / 8, 256, 0, stream>>>(P, colptr, esrow, aggh, aggl, N, E);
    uw_kernel<<<B, 128, 0, stream>>>(uin, n2w1 + (size_t)l * 384 * 128,
                                     n2b1 + l * 128, UW);
    node_mfma<<<NB, 256, 0, stream>>>(
        xhi, xlo, aggh, aggl, UW, batch,
        w1t_n + (size_t)l * 65536, w2t_n + (size_t)l * 32768,
        n2b2 + l * 128, xout, N);
    gsum_kernel<<<512, 128, 0, stream>>>(xout, batch, gx, N);
    gmlp_kernel<<<B, 128, 0, stream>>>(
        uin, gx, gcnt,
        gw1 + (size_t)l * 256 * 128, gb1 + l * 128,
        gw2 + (size_t)l * 128 * 128, gb2 + l * 128, uout);
  }
}

// Round 5
// 870.224 us; speedup vs baseline: 2.0638x; 1.2624x over previous
//
#include <hip/hip_runtime.h>

typedef __bf16 bf16;
typedef bf16 bf16x8 __attribute__((ext_vector_type(8)));
typedef bf16 bf16x4 __attribute__((ext_vector_type(4)));
typedef float floatx4 __attribute__((ext_vector_type(4)));

#define MFMA __builtin_amdgcn_mfma_f32_16x16x32_bf16

// ---------------- setup kernels ----------------

__global__ void hist_kernel(const int* __restrict__ ei, int* __restrict__ cnt, int E) {
  int e = blockIdx.x * blockDim.x + threadIdx.x;
  if (e < E) atomicAdd(&cnt[ei[E + e]], 1);
}

__global__ void gcnt_kernel(const int* __restrict__ batch, int* __restrict__ gcnt,
                            int N, int B) {
  const int b = threadIdx.x;
  if (b >= B) return;
  auto lb = [&](int v) {
    int lo = 0, hi = N;
    while (lo < hi) {
      const int mid = (lo + hi) >> 1;
      if (batch[mid] < v) lo = mid + 1; else hi = mid;
    }
    return lo;
  };
  gcnt[b] = lb(b + 1) - lb(b);
}

__global__ void scan1_kernel(const int* __restrict__ cnt, int* __restrict__ colptr,
                             int* __restrict__ rctr, int* __restrict__ btot, int n) {
  __shared__ int sd[256];
  const int tid = threadIdx.x;
  const int i0 = blockIdx.x * 2048 + tid * 8;
  int v[8];
  int tot = 0;
#pragma unroll
  for (int j = 0; j < 8; ++j) {
    const int i = i0 + j;
    v[j] = (i < n) ? cnt[i] : 0;
    tot += v[j];
  }
  sd[tid] = tot;
  __syncthreads();
  for (int off = 1; off < 256; off <<= 1) {
    const int t = (tid >= off) ? sd[tid - off] : 0;
    __syncthreads();
    sd[tid] += t;
    __syncthreads();
  }
  int excl = sd[tid] - tot;
#pragma unroll
  for (int j = 0; j < 8; ++j) {
    const int i = i0 + j;
    if (i < n) { colptr[i] = excl; rctr[i] = excl; }
    excl += v[j];
  }
  if (tid == 255) btot[blockIdx.x] = sd[255];
}

__global__ void scan2_kernel(int* __restrict__ colptr, int* __restrict__ rctr,
                             const int* __restrict__ btot, int n) {
  __shared__ int off_s;
  const int tid = threadIdx.x;
  if (blockIdx.x == 0) return;
  if (tid == 0) {
    int o = 0;
    for (int j = 0; j < (int)blockIdx.x; ++j) o += btot[j];
    off_s = o;
  }
  __syncthreads();
  const int off = off_s;
  const int i0 = blockIdx.x * 2048 + tid * 8;
#pragma unroll
  for (int j = 0; j < 8; ++j) {
    const int i = i0 + j;
    if (i < n) { colptr[i] += off; rctr[i] += off; }
  }
}

__global__ void place_kernel(const int* __restrict__ ei, int* __restrict__ rctr,
                             int* __restrict__ esrow, int E) {
  int e = blockIdx.x * blockDim.x + threadIdx.x;
  if (e >= E) return;
  const int r = ei[e];
  const int c = ei[E + e];
  const int p = atomicAdd(&rctr[c], 1);
  esrow[p] = r;
}

// transpose+split: src [L][Ksrc][H] fp32 (first K rows) -> dst [L][2][H][K] bf16
__global__ void wsplit_kernel(const float* __restrict__ src, bf16* __restrict__ dst,
                              int Ksrc, int K, int HH) {
  const int l = blockIdx.y;
  const int gid = blockIdx.x * blockDim.x + threadIdx.x;
  if (gid >= K * HH) return;
  const int h = gid / K, k = gid - h * K;
  const float v = src[(size_t)l * Ksrc * HH + (size_t)k * HH + h];
  const bf16 hi = (bf16)v;
  const bf16 lo = (bf16)(v - (float)hi);
  bf16* d = dst + (size_t)l * 2 * K * HH;
  d[(size_t)h * K + k] = hi;
  d[(size_t)K * HH + (size_t)h * K + k] = lo;
}

__global__ void xsplit_kernel(const float* __restrict__ x, bf16* __restrict__ xhi,
                              bf16* __restrict__ xlo, int n4) {
  const int i = blockIdx.x * 256 + threadIdx.x;
  if (i >= n4) return;
  const float4 v = ((const float4*)x)[i];
  bf16x4 h, l;
  const float vv[4] = {v.x, v.y, v.z, v.w};
#pragma unroll
  for (int r = 0; r < 4; ++r) {
    h[r] = (bf16)vv[r];
    l[r] = (bf16)(vv[r] - (float)h[r]);
  }
  *(bf16x4*)&xhi[(size_t)i * 4] = h;
  *(bf16x4*)&xlo[(size_t)i * 4] = l;
}

// ---------------- edge MLP per NODE: P = relu(X@W1+b1)@W2+b2 -------------
__global__ __launch_bounds__(256, 3)
void pnode_mfma(const bf16* __restrict__ xh, const bf16* __restrict__ xl,
                const bf16* __restrict__ w1t, const float* __restrict__ b1,
                const bf16* __restrict__ w2t, const float* __restrict__ b2,
                bf16* __restrict__ P, int N) {
  __shared__ __align__(16) bf16 H1[2][64 * 136];

  const int tid = threadIdx.x;
  const int n0 = blockIdx.x * 64;
  const int wave = tid >> 6, lane = tid & 63, q = lane >> 4, lr = lane & 15;
  const int hbase = wave * 32;

  int nn[4];
#pragma unroll
  for (int nt = 0; nt < 4; ++nt) {
    int n = n0 + nt * 16 + lr;
    nn[nt] = (n > N - 1) ? (N - 1) : n;
  }

  const floatx4 zz = {0.f, 0.f, 0.f, 0.f};
  floatx4 acc[2][4];
#pragma unroll
  for (int mt = 0; mt < 2; ++mt)
#pragma unroll
    for (int nt = 0; nt < 4; ++nt) acc[mt][nt] = zz;

  // GEMM1: K=128, B-fragments double-buffered (prefetch next kc)
  bf16x8 bh[2][4], bl[2][4];
#pragma unroll
  for (int nt = 0; nt < 4; ++nt) {
    const size_t off = (size_t)nn[nt] * 128 + q * 8;
    bh[0][nt] = *(const bf16x8*)(xh + off);
    bl[0][nt] = *(const bf16x8*)(xl + off);
  }
#pragma unroll
  for (int kc = 0; kc < 4; ++kc) {
    const int cur = kc & 1, nxt = cur ^ 1;
    if (kc < 3) {
#pragma unroll
      for (int nt = 0; nt < 4; ++nt) {
        const size_t off = (size_t)nn[nt] * 128 + (kc + 1) * 32 + q * 8;
        bh[nxt][nt] = *(const bf16x8*)(xh + off);
        bl[nxt][nt] = *(const bf16x8*)(xl + off);
      }
    }
    bf16x8 ah[2], al[2];
#pragma unroll
    for (int mt = 0; mt < 2; ++mt) {
      const bf16* wp = w1t + (size_t)(hbase + mt * 16 + lr) * 128 + kc * 32 + q * 8;
      ah[mt] = *(const bf16x8*)wp;
      al[mt] = *(const bf16x8*)(wp + 16384);
    }
#pragma unroll
    for (int nt = 0; nt < 4; ++nt)
#pragma unroll
      for (int mt = 0; mt < 2; ++mt) {
        acc[mt][nt] = MFMA(ah[mt], bh[cur][nt], acc[mt][nt], 0, 0, 0);
        acc[mt][nt] = MFMA(al[mt], bh[cur][nt], acc[mt][nt], 0, 0, 0);
        acc[mt][nt] = MFMA(ah[mt], bl[cur][nt], acc[mt][nt], 0, 0, 0);
      }
  }

  // epilogue 1: bias+relu, split -> H1[e][h]
#pragma unroll
  for (int mt = 0; mt < 2; ++mt) {
    const int h0 = hbase + mt * 16 + q * 4;
    const float* bp = &b1[h0];
#pragma unroll
    for (int nt = 0; nt < 4; ++nt) {
      const int e = nt * 16 + lr;
      bf16x4 hh, ll;
#pragma unroll
      for (int r = 0; r < 4; ++r) {
        const float v = fmaxf(acc[mt][nt][r] + bp[r], 0.f);
        hh[r] = (bf16)v;
        ll[r] = (bf16)(v - (float)hh[r]);
      }
      *(bf16x4*)&H1[0][e * 136 + h0] = hh;
      *(bf16x4*)&H1[1][e * 136 + h0] = ll;
      acc[mt][nt] = zz;
    }
  }
  __syncthreads();

  // GEMM2
#pragma unroll
  for (int ks = 0; ks < 4; ++ks) {
    bf16x8 ah[2], al[2], b2h[4], b2l[4];
#pragma unroll
    for (int mt = 0; mt < 2; ++mt) {
      const bf16* wp = w2t + (size_t)(hbase + mt * 16 + lr) * 128 + ks * 32 + q * 8;
      ah[mt] = *(const bf16x8*)wp;
      al[mt] = *(const bf16x8*)(wp + 16384);
    }
#pragma unroll
    for (int nt = 0; nt < 4; ++nt) {
      const bf16* hp = &H1[0][(nt * 16 + lr) * 136 + ks * 32 + q * 8];
      b2h[nt] = *(const bf16x8*)hp;
      b2l[nt] = *(const bf16x8*)(hp + 64 * 136);
    }
#pragma unroll
    for (int nt = 0; nt < 4; ++nt)
#pragma unroll
      for (int mt = 0; mt < 2; ++mt) {
        acc[mt][nt] = MFMA(ah[mt], b2h[nt], acc[mt][nt], 0, 0, 0);
        acc[mt][nt] = MFMA(al[mt], b2h[nt], acc[mt][nt], 0, 0, 0);
        acc[mt][nt] = MFMA(ah[mt], b2l[nt], acc[mt][nt], 0, 0, 0);
      }
  }

  // epilogue 2: +b2, store P bf16
#pragma unroll
  for (int mt = 0; mt < 2; ++mt) {
    const int f0 = hbase + mt * 16 + q * 4;
    const float* bp = &b2[f0];
#pragma unroll
    for (int nt = 0; nt < 4; ++nt) {
      const int n = n0 + nt * 16 + lr;
      if (n < N) {
        bf16x4 o;
#pragma unroll
        for (int r = 0; r < 4; ++r) o[r] = (bf16)(acc[mt][nt][r] + bp[r]);
        *(bf16x4*)&P[(size_t)n * 128 + f0] = o;
      }
    }
  }
}

// ---------------- CSR mean-aggregate, 8-deep MLP -------------------------
// one col per 128-thread group; 8 outstanding gathers/lane, 4 accumulators
__global__ __launch_bounds__(256)
void agg_csr(const bf16* __restrict__ P, const int* __restrict__ colptr,
             const int* __restrict__ esrow,
             bf16* __restrict__ aggh, bf16* __restrict__ aggl, int N, int E) {
  const int f = threadIdx.x & 127;
  const int c = blockIdx.x * 2 + (threadIdx.x >> 7);
  if (c >= N) return;
  const int beg = colptr[c];
  const int end = (c == N - 1) ? E : colptr[c + 1];
  float sacc[4] = {0.f, 0.f, 0.f, 0.f};
  int e = beg;
  for (; e + 8 <= end; e += 8) {
    int r[8];
#pragma unroll
    for (int j = 0; j < 8; ++j) r[j] = esrow[e + j];
    float v[8];
#pragma unroll
    for (int j = 0; j < 8; ++j) v[j] = (float)P[(size_t)r[j] * 128 + f];
#pragma unroll
    for (int j = 0; j < 8; ++j) sacc[j & 3] += v[j];
  }
  const int rem = end - e;
  if (rem > 0) {
    int r[8];
#pragma unroll
    for (int j = 0; j < 8; ++j) r[j] = esrow[e + (j < rem ? j : 0)];
#pragma unroll
    for (int j = 0; j < 8; ++j) {
      const float v = (float)P[(size_t)r[j] * 128 + f];
      if (j < rem) sacc[j & 3] += v;
    }
  }
  const int cc = end - beg;
  const float val = ((sacc[0] + sacc[1]) + (sacc[2] + sacc[3])) /
                    (float)(cc > 1 ? cc : 1);
  const bf16 h = (bf16)val;
  aggh[(size_t)c * 128 + f] = h;
  aggl[(size_t)c * 128 + f] = (bf16)(val - (float)h);
}

// ---------------- UW = u @ W1c + b1 (64 distinct u rows) -----------------
__global__ void uw_kernel(const float* __restrict__ u, const float* __restrict__ w1,
                          const float* __restrict__ b1, float* __restrict__ UW) {
  const int b = blockIdx.x, h = threadIdx.x;
  float s = b1[h];
#pragma unroll 8
  for (int k = 0; k < 128; ++k)
    s = fmaf(u[b * 128 + k], w1[(size_t)(256 + k) * 128 + h], s);
  UW[b * 128 + h] = s;
}

// ---------------- node MLP: K=256, acc init UW[batch], fused gsum --------
__global__ __launch_bounds__(256, 3)
void node_mfma(bf16* xh, bf16* xl,
               const bf16* __restrict__ aggh, const bf16* __restrict__ aggl,
               const float* __restrict__ UW, const int* __restrict__ batch,
               const bf16* __restrict__ w1t, const bf16* __restrict__ w2t,
               const float* __restrict__ b2, float* __restrict__ gx,
               float* __restrict__ xout, int write_x, int N) {
  __shared__ __align__(16) bf16 H1[2][64 * 136];   // reused as Xt fp32 [128][65]
  __shared__ int sbatch[64];

  const int tid = threadIdx.x;
  const int n0 = blockIdx.x * 64;
  const int wave = tid >> 6, lane = tid & 63, q = lane >> 4, lr = lane & 15;
  const int hbase = wave * 32;

  if (tid < 64) {
    int n = n0 + tid;
    sbatch[tid] = batch[(n > N - 1) ? (N - 1) : n];
  }

  int nn[4], ub[4];
#pragma unroll
  for (int nt = 0; nt < 4; ++nt) {
    int n = n0 + nt * 16 + lr;
    if (n > N - 1) n = N - 1;
    nn[nt] = n;
    ub[nt] = batch[n];
  }

  floatx4 acc[2][4];
#pragma unroll
  for (int mt = 0; mt < 2; ++mt)
#pragma unroll
    for (int nt = 0; nt < 4; ++nt)
      acc[mt][nt] = *(const floatx4*)&UW[(size_t)ub[nt] * 128 + hbase + mt * 16 + q * 4];

  // GEMM1: K=256 (x hi/lo | agg hi/lo), B double-buffered
  bf16x8 bh[2][4], bl[2][4];
  auto loadB = [&](int kc, int buf) {
#pragma unroll
    for (int nt = 0; nt < 4; ++nt) {
      if (kc < 4) {
        const size_t off = (size_t)nn[nt] * 128 + kc * 32 + q * 8;
        bh[buf][nt] = *(const bf16x8*)(xh + off);
        bl[buf][nt] = *(const bf16x8*)(xl + off);
      } else {
        const size_t off = (size_t)nn[nt] * 128 + (kc - 4) * 32 + q * 8;
        bh[buf][nt] = *(const bf16x8*)(aggh + off);
        bl[buf][nt] = *(const bf16x8*)(aggl + off);
      }
    }
  };
  loadB(0, 0);
#pragma unroll
  for (int kc = 0; kc < 8; ++kc) {
    const int cur = kc & 1, nxt = cur ^ 1;
    if (kc < 7) loadB(kc + 1, nxt);
    bf16x8 ah[2], al[2];
#pragma unroll
    for (int mt = 0; mt < 2; ++mt) {
      const bf16* wp = w1t + (size_t)(hbase + mt * 16 + lr) * 256 + kc * 32 + q * 8;
      ah[mt] = *(const bf16x8*)wp;
      al[mt] = *(const bf16x8*)(wp + 32768);
    }
#pragma unroll
    for (int nt = 0; nt < 4; ++nt)
#pragma unroll
      for (int mt = 0; mt < 2; ++mt) {
        acc[mt][nt] = MFMA(ah[mt], bh[cur][nt], acc[mt][nt], 0, 0, 0);
        acc[mt][nt] = MFMA(al[mt], bh[cur][nt], acc[mt][nt], 0, 0, 0);
        acc[mt][nt] = MFMA(ah[mt], bl[cur][nt], acc[mt][nt], 0, 0, 0);
      }
  }

  // epilogue 1: relu (b1 folded into UW), split -> H1
  const floatx4 zz = {0.f, 0.f, 0.f, 0.f};
#pragma unroll
  for (int mt = 0; mt < 2; ++mt) {
    const int h0 = hbase + mt * 16 + q * 4;
#pragma unroll
    for (int nt = 0; nt < 4; ++nt) {
      const int e = nt * 16 + lr;
      bf16x4 hh, ll;
#pragma unroll
      for (int r = 0; r < 4; ++r) {
        const float v = fmaxf(acc[mt][nt][r], 0.f);
        hh[r] = (bf16)v;
        ll[r] = (bf16)(v - (float)hh[r]);
      }
      *(bf16x4*)&H1[0][e * 136 + h0] = hh;
      *(bf16x4*)&H1[1][e * 136 + h0] = ll;
      acc[mt][nt] = zz;
    }
  }
  __syncthreads();

  // GEMM2
#pragma unroll
  for (int ks = 0; ks < 4; ++ks) {
    bf16x8 ah[2], al[2], b2h[4], b2l[4];
#pragma unroll
    for (int mt = 0; mt < 2; ++mt) {
      const bf16* wp = w2t + (size_t)(hbase + mt * 16 + lr) * 128 + ks * 32 + q * 8;
      ah[mt] = *(const bf16x8*)wp;
      al[mt] = *(const bf16x8*)(wp + 16384);
    }
#pragma unroll
    for (int nt = 0; nt < 4; ++nt) {
      const bf16* hp = &H1[0][(nt * 16 + lr) * 136 + ks * 32 + q * 8];
      b2h[nt] = *(const bf16x8*)hp;
      b2l[nt] = *(const bf16x8*)(hp + 64 * 136);
    }
#pragma unroll
    for (int nt = 0; nt < 4; ++nt)
#pragma unroll
      for (int mt = 0; mt < 2; ++mt) {
        acc[mt][nt] = MFMA(ah[mt], b2h[nt], acc[mt][nt], 0, 0, 0);
        acc[mt][nt] = MFMA(al[mt], b2h[nt], acc[mt][nt], 0, 0, 0);
        acc[mt][nt] = MFMA(ah[mt], b2l[nt], acc[mt][nt], 0, 0, 0);
      }
  }
  __syncthreads();   // all H1 reads done; Xt fp32 overlays H1

  // epilogue 2: +b2 -> Xt LDS tile + xh/xl global (+ xout if last layer)
  float* Xt = (float*)&H1[0][0];
#pragma unroll
  for (int mt = 0; mt < 2; ++mt) {
    const int f0 = hbase + mt * 16 + q * 4;
    const float* bp = &b2[f0];
#pragma unroll
    for (int nt = 0; nt < 4; ++nt) {
      const int n = n0 + nt * 16 + lr;
      const int e = nt * 16 + lr;
      float vv[4];
      bf16x4 hh, ll;
#pragma unroll
      for (int r = 0; r < 4; ++r) {
        vv[r] = acc[mt][nt][r] + bp[r];
        Xt[(f0 + r) * 65 + e] = (n < N) ? vv[r] : 0.f;
        hh[r] = (bf16)vv[r];
        ll[r] = (bf16)(vv[r] - (float)hh[r]);
      }
      if (n < N) {
        *(bf16x4*)&xh[(size_t)n * 128 + f0] = hh;
        *(bf16x4*)&xl[(size_t)n * 128 + f0] = ll;
        if (write_x) {
          float4 o;
          o.x = vv[0]; o.y = vv[1]; o.z = vv[2]; o.w = vv[3];
          *(float4*)&xout[(size_t)n * 128 + f0] = o;
        }
      }
    }
  }
  __syncthreads();

  // fused gsum: segmented reduce over 64 sorted-batch nodes, ~1 atomic/f
  {
    const int f = tid & 127;
    const int es = (tid >> 7) * 32;
    int cur = sbatch[es];
    float s = 0.f;
    for (int e = es; e < es + 32; ++e) {
      const int b = sbatch[e];
      const float v = Xt[f * 65 + e];
      if (b != cur) {
        atomicAdd(&gx[(size_t)cur * 128 + f], s);
        s = 0.f;
        cur = b;
      }
      s += v;
    }
    atomicAdd(&gx[(size_t)cur * 128 + f], s);
  }
}

// ---------------- global MLP (zeroes its gx row for next layer) ----------
__global__ __launch_bounds__(128)
void gmlp_kernel(const float* __restrict__ uin, float* __restrict__ gx,
                 const int* __restrict__ gcnt,
                 const float* __restrict__ gw1, const float* __restrict__ gb1,
                 const float* __restrict__ gw2, const float* __restrict__ gb2,
                 float* __restrict__ uout) {
  __shared__ float g[256];
  __shared__ float g1[128];
  const int b = blockIdx.x;
  const int t = threadIdx.x;
  const int c = gcnt[b];
  const float inv = 1.f / (float)(c > 1 ? c : 1);
  g[t] = uin[b * 128 + t];
  g[128 + t] = gx[b * 128 + t] * inv;
  gx[b * 128 + t] = 0.f;
  __syncthreads();
  float acc = gb1[t];
#pragma unroll 8
  for (int k = 0; k < 256; ++k) acc = fmaf(g[k], gw1[k * 128 + t], acc);
  g1[t] = fmaxf(acc, 0.f);
  __syncthreads();
  float acc2 = gb2[t];
#pragma unroll 8
  for (int k = 0; k < 128; ++k) acc2 = fmaf(g1[k], gw2[k * 128 + t], acc2);
  uout[b * 128 + t] = acc2;
}

// ---------------- host ----------------
extern "C" void kernel_launch(void* const* d_in, const int* in_sizes, int n_in,
                              void* d_out, int out_size, void* d_ws, size_t ws_size,
                              hipStream_t stream) {
  constexpr int N = 50000, E = 600000, B = 64, F = 128, L = 4;

  const float* x0    = (const float*)d_in[0];
  const int*   ei    = (const int*)  d_in[1];
  const float* u0    = (const float*)d_in[2];
  const int*   batch = (const int*)  d_in[3];
  const float* n1w1  = (const float*)d_in[4];
  const float* n1b1  = (const float*)d_in[5];
  const float* n1w2  = (const float*)d_in[6];
  const float* n1b2  = (const float*)d_in[7];
  const float* n2w1  = (const float*)d_in[8];
  const float* n2b1  = (const float*)d_in[9];
  const float* n2w2  = (const float*)d_in[10];
  const float* n2b2  = (const float*)d_in[11];
  const float* gw1   = (const float*)d_in[12];
  const float* gb1   = (const float*)d_in[13];
  const float* gw2   = (const float*)d_in[14];
  const float* gb2   = (const float*)d_in[15];
  float* out = (float*)d_out;

  char* p = (char*)d_ws;
  auto carve = [&](size_t bytes) -> void* {
    void* q = (void*)p;
    p += (bytes + 255) & ~(size_t)255;
    return q;
  };
  float* ubuf  = (float*)carve((size_t)B * F * 4);
  float* gx    = (float*)carve((size_t)B * F * 4);
  float* UW    = (float*)carve((size_t)B * F * 4);
  int*   cnt   = (int*)carve((size_t)N * 4);
  int*   colptr= (int*)carve((size_t)(N + 1) * 4);
  int*   rctr  = (int*)carve((size_t)N * 4);
  int*   gcnt  = (int*)carve((size_t)B * 4);
  int*   btot  = (int*)carve(32 * 4);
  int*   esrow = (int*)carve((size_t)E * 4);
  bf16*  xhi   = (bf16*)carve((size_t)N * F * 2);
  bf16*  xlo   = (bf16*)carve((size_t)N * F * 2);
  bf16*  P     = (bf16*)carve((size_t)N * F * 2);
  bf16*  aggh  = (bf16*)carve((size_t)N * F * 2);
  bf16*  aggl  = (bf16*)carve((size_t)N * F * 2);
  bf16*  w1t_e = (bf16*)carve((size_t)L * 2 * 128 * 128 * 2);
  bf16*  w2t_e = (bf16*)carve((size_t)L * 2 * 128 * 128 * 2);
  bf16*  w1t_n = (bf16*)carve((size_t)L * 2 * 256 * 128 * 2);
  bf16*  w2t_n = (bf16*)carve((size_t)L * 2 * 128 * 128 * 2);

  constexpr int SCAN_BLOCKS = (N + 2047) / 2048;

  hipMemsetAsync(cnt, 0, (size_t)N * 4, stream);
  hipMemsetAsync(gx, 0, (size_t)B * F * 4, stream);   // re-zeroed by gmlp
  hist_kernel<<<(E + 255) / 256, 256, 0, stream>>>(ei, cnt, E);
  gcnt_kernel<<<1, 64, 0, stream>>>(batch, gcnt, N, B);
  scan1_kernel<<<SCAN_BLOCKS, 256, 0, stream>>>(cnt, colptr, rctr, btot, N);
  scan2_kernel<<<SCAN_BLOCKS, 256, 0, stream>>>(colptr, rctr, btot, N);
  place_kernel<<<(E + 255) / 256, 256, 0, stream>>>(ei, rctr, esrow, E);
  wsplit_kernel<<<dim3(64, L), 256, 0, stream>>>(n1w1, w1t_e, 128, 128, 128);
  wsplit_kernel<<<dim3(64, L), 256, 0, stream>>>(n1w2, w2t_e, 128, 128, 128);
  wsplit_kernel<<<dim3(128, L), 256, 0, stream>>>(n2w1, w1t_n, 384, 256, 128);
  wsplit_kernel<<<dim3(64, L), 256, 0, stream>>>(n2w2, w2t_n, 128, 128, 128);
  xsplit_kernel<<<(N * F / 4 + 255) / 256, 256, 0, stream>>>(x0, xhi, xlo, N * F / 4);

  const int NB = (N + 63) / 64;
  for (int l = 0; l < L; ++l) {
    const float* uin  = l ? ubuf : u0;
    float*       uout = (l == L - 1) ? out + (size_t)N * F : ubuf;
    const int    wx   = (l == L - 1) ? 1 : 0;

    pnode_mfma<<<NB, 256, 0, stream>>>(
        xhi, xlo,
        w1t_e + (size_t)l * 32768, n1b1 + l * 128,
        w2t_e + (size_t)l * 32768, n1b2 + l * 128, P, N);
    agg_csr<<<(N + 1) / 2, 256, 0, stream>>>(P, colptr, esrow, aggh, aggl, N, E);
    uw_kernel<<<B, 128, 0, stream>>>(uin, n2w1 + (size_t)l * 384 * 128,
                                     n2b1 + l * 128, UW);
    node_mfma<<<NB, 256, 0, stream>>>(
        xhi, xlo, aggh, aggl, UW, batch,
        w1t_n + (size_t)l * 65536, w2t_n + (size_t)l * 32768,
        n2b2 + l * 128, gx, out, wx, N);
    gmlp_kernel<<<B, 128, 0, stream>>>(
        uin, gx, gcnt,
        gw1 + (size_t)l * 256 * 128, gb1 + l * 128,
        gw2 + (size_t)l * 128 * 128, gb2 + l * 128, uout);
  }
}

// Round 6
// 857.499 us; speedup vs baseline: 2.0944x; 1.0148x over previous
//
#include <hip/hip_runtime.h>

typedef __bf16 bf16;
typedef bf16 bf16x8 __attribute__((ext_vector_type(8)));
typedef bf16 bf16x4 __attribute__((ext_vector_type(4)));
typedef float floatx4 __attribute__((ext_vector_type(4)));

#define MFMA __builtin_amdgcn_mfma_f32_16x16x32_bf16

// ---------------- setup kernels ----------------

__global__ void hist_kernel(const int* __restrict__ ei, int* __restrict__ cnt, int E) {
  int e = blockIdx.x * blockDim.x + threadIdx.x;
  if (e < E) atomicAdd(&cnt[ei[E + e]], 1);
}

__global__ void gcnt_kernel(const int* __restrict__ batch, int* __restrict__ gcnt,
                            int N, int B) {
  const int b = threadIdx.x;
  if (b >= B) return;
  auto lb = [&](int v) {
    int lo = 0, hi = N;
    while (lo < hi) {
      const int mid = (lo + hi) >> 1;
      if (batch[mid] < v) lo = mid + 1; else hi = mid;
    }
    return lo;
  };
  gcnt[b] = lb(b + 1) - lb(b);
}

__global__ void scan1_kernel(const int* __restrict__ cnt, int* __restrict__ colptr,
                             int* __restrict__ rctr, int* __restrict__ btot, int n) {
  __shared__ int sd[256];
  const int tid = threadIdx.x;
  const int i0 = blockIdx.x * 2048 + tid * 8;
  int v[8];
  int tot = 0;
#pragma unroll
  for (int j = 0; j < 8; ++j) {
    const int i = i0 + j;
    v[j] = (i < n) ? cnt[i] : 0;
    tot += v[j];
  }
  sd[tid] = tot;
  __syncthreads();
  for (int off = 1; off < 256; off <<= 1) {
    const int t = (tid >= off) ? sd[tid - off] : 0;
    __syncthreads();
    sd[tid] += t;
    __syncthreads();
  }
  int excl = sd[tid] - tot;
#pragma unroll
  for (int j = 0; j < 8; ++j) {
    const int i = i0 + j;
    if (i < n) { colptr[i] = excl; rctr[i] = excl; }
    excl += v[j];
  }
  if (tid == 255) btot[blockIdx.x] = sd[255];
}

__global__ void scan2_kernel(int* __restrict__ colptr, int* __restrict__ rctr,
                             const int* __restrict__ btot, int n) {
  __shared__ int off_s;
  const int tid = threadIdx.x;
  if (blockIdx.x == 0) return;
  if (tid == 0) {
    int o = 0;
    for (int j = 0; j < (int)blockIdx.x; ++j) o += btot[j];
    off_s = o;
  }
  __syncthreads();
  const int off = off_s;
  const int i0 = blockIdx.x * 2048 + tid * 8;
#pragma unroll
  for (int j = 0; j < 8; ++j) {
    const int i = i0 + j;
    if (i < n) { colptr[i] += off; rctr[i] += off; }
  }
}

__global__ void place_kernel(const int* __restrict__ ei, int* __restrict__ rctr,
                             int* __restrict__ esrow, int E) {
  int e = blockIdx.x * blockDim.x + threadIdx.x;
  if (e >= E) return;
  const int r = ei[e];
  const int c = ei[E + e];
  const int p = atomicAdd(&rctr[c], 1);
  esrow[p] = r;
}

// transpose+split: src [L][Ksrc][H] fp32 (first K rows) -> dst [L][2][H][K] bf16
__global__ void wsplit_kernel(const float* __restrict__ src, bf16* __restrict__ dst,
                              int Ksrc, int K, int HH) {
  const int l = blockIdx.y;
  const int gid = blockIdx.x * blockDim.x + threadIdx.x;
  if (gid >= K * HH) return;
  const int h = gid / K, k = gid - h * K;
  const float v = src[(size_t)l * Ksrc * HH + (size_t)k * HH + h];
  const bf16 hi = (bf16)v;
  const bf16 lo = (bf16)(v - (float)hi);
  bf16* d = dst + (size_t)l * 2 * K * HH;
  d[(size_t)h * K + k] = hi;
  d[(size_t)K * HH + (size_t)h * K + k] = lo;
}

__global__ void xsplit_kernel(const float* __restrict__ x, bf16* __restrict__ xhi,
                              bf16* __restrict__ xlo, int n4) {
  const int i = blockIdx.x * 256 + threadIdx.x;
  if (i >= n4) return;
  const float4 v = ((const float4*)x)[i];
  bf16x4 h, l;
  const float vv[4] = {v.x, v.y, v.z, v.w};
#pragma unroll
  for (int r = 0; r < 4; ++r) {
    h[r] = (bf16)vv[r];
    l[r] = (bf16)(vv[r] - (float)h[r]);
  }
  *(bf16x4*)&xhi[(size_t)i * 4] = h;
  *(bf16x4*)&xlo[(size_t)i * 4] = l;
}

// ---------------- edge MLP per NODE: P = relu(X@W1+b1)@W2+b2 -------------
__global__ __launch_bounds__(256, 4)
void pnode_mfma(const bf16* __restrict__ xh, const bf16* __restrict__ xl,
                const bf16* __restrict__ w1t, const float* __restrict__ b1,
                const bf16* __restrict__ w2t, const float* __restrict__ b2,
                bf16* __restrict__ P, int N) {
  __shared__ __align__(16) bf16 H1[2][64 * 136];   // reused as P tile [64][136] bf16

  const int tid = threadIdx.x;
  const int n0 = blockIdx.x * 64;
  const int wave = tid >> 6, lane = tid & 63, q = lane >> 4, lr = lane & 15;
  const int hbase = wave * 32;

  int nn[4];
#pragma unroll
  for (int nt = 0; nt < 4; ++nt) {
    int n = n0 + nt * 16 + lr;
    nn[nt] = (n > N - 1) ? (N - 1) : n;
  }

  const floatx4 zz = {0.f, 0.f, 0.f, 0.f};
  floatx4 acc[2][4];
#pragma unroll
  for (int mt = 0; mt < 2; ++mt)
#pragma unroll
    for (int nt = 0; nt < 4; ++nt) acc[mt][nt] = zz;

  // GEMM1: K=128, B-fragments double-buffered
  bf16x8 bh[2][4], bl[2][4];
#pragma unroll
  for (int nt = 0; nt < 4; ++nt) {
    const size_t off = (size_t)nn[nt] * 128 + q * 8;
    bh[0][nt] = *(const bf16x8*)(xh + off);
    bl[0][nt] = *(const bf16x8*)(xl + off);
  }
#pragma unroll
  for (int kc = 0; kc < 4; ++kc) {
    const int cur = kc & 1, nxt = cur ^ 1;
    if (kc < 3) {
#pragma unroll
      for (int nt = 0; nt < 4; ++nt) {
        const size_t off = (size_t)nn[nt] * 128 + (kc + 1) * 32 + q * 8;
        bh[nxt][nt] = *(const bf16x8*)(xh + off);
        bl[nxt][nt] = *(const bf16x8*)(xl + off);
      }
    }
    bf16x8 ah[2], al[2];
#pragma unroll
    for (int mt = 0; mt < 2; ++mt) {
      const bf16* wp = w1t + (size_t)(hbase + mt * 16 + lr) * 128 + kc * 32 + q * 8;
      ah[mt] = *(const bf16x8*)wp;
      al[mt] = *(const bf16x8*)(wp + 16384);
    }
#pragma unroll
    for (int nt = 0; nt < 4; ++nt)
#pragma unroll
      for (int mt = 0; mt < 2; ++mt) {
        acc[mt][nt] = MFMA(ah[mt], bh[cur][nt], acc[mt][nt], 0, 0, 0);
        acc[mt][nt] = MFMA(al[mt], bh[cur][nt], acc[mt][nt], 0, 0, 0);
        acc[mt][nt] = MFMA(ah[mt], bl[cur][nt], acc[mt][nt], 0, 0, 0);
      }
  }

  // epilogue 1: bias+relu, split -> H1[e][h]
#pragma unroll
  for (int mt = 0; mt < 2; ++mt) {
    const int h0 = hbase + mt * 16 + q * 4;
    const float* bp = &b1[h0];
#pragma unroll
    for (int nt = 0; nt < 4; ++nt) {
      const int e = nt * 16 + lr;
      bf16x4 hh, ll;
#pragma unroll
      for (int r = 0; r < 4; ++r) {
        const float v = fmaxf(acc[mt][nt][r] + bp[r], 0.f);
        hh[r] = (bf16)v;
        ll[r] = (bf16)(v - (float)hh[r]);
      }
      *(bf16x4*)&H1[0][e * 136 + h0] = hh;
      *(bf16x4*)&H1[1][e * 136 + h0] = ll;
      acc[mt][nt] = zz;
    }
  }
  __syncthreads();

  // GEMM2
#pragma unroll
  for (int ks = 0; ks < 4; ++ks) {
    bf16x8 ah[2], al[2], b2h[4], b2l[4];
#pragma unroll
    for (int mt = 0; mt < 2; ++mt) {
      const bf16* wp = w2t + (size_t)(hbase + mt * 16 + lr) * 128 + ks * 32 + q * 8;
      ah[mt] = *(const bf16x8*)wp;
      al[mt] = *(const bf16x8*)(wp + 16384);
    }
#pragma unroll
    for (int nt = 0; nt < 4; ++nt) {
      const bf16* hp = &H1[0][(nt * 16 + lr) * 136 + ks * 32 + q * 8];
      b2h[nt] = *(const bf16x8*)hp;
      b2l[nt] = *(const bf16x8*)(hp + 64 * 136);
    }
#pragma unroll
    for (int nt = 0; nt < 4; ++nt)
#pragma unroll
      for (int mt = 0; mt < 2; ++mt) {
        acc[mt][nt] = MFMA(ah[mt], b2h[nt], acc[mt][nt], 0, 0, 0);
        acc[mt][nt] = MFMA(al[mt], b2h[nt], acc[mt][nt], 0, 0, 0);
        acc[mt][nt] = MFMA(ah[mt], b2l[nt], acc[mt][nt], 0, 0, 0);
      }
  }
  __syncthreads();   // H1 reads done; P tile overlays H1

  // epilogue 2: +b2 -> P tile in LDS, then coalesced global store
  bf16* Pl = &H1[0][0];
#pragma unroll
  for (int mt = 0; mt < 2; ++mt) {
    const int f0 = hbase + mt * 16 + q * 4;
    const float* bp = &b2[f0];
#pragma unroll
    for (int nt = 0; nt < 4; ++nt) {
      const int e = nt * 16 + lr;
      bf16x4 o;
#pragma unroll
      for (int r = 0; r < 4; ++r) o[r] = (bf16)(acc[mt][nt][r] + bp[r]);
      *(bf16x4*)&Pl[e * 136 + f0] = o;
    }
  }
  __syncthreads();
#pragma unroll
  for (int it = 0; it < 4; ++it) {
    const int idx = it * 256 + tid;
    const int row = idx >> 4;
    const int f8 = (idx & 15) * 8;
    const int n = n0 + row;
    if (n < N)
      *(bf16x8*)&P[(size_t)n * 128 + f8] = *(const bf16x8*)&Pl[row * 136 + f8];
  }
}

// ---------------- CSR mean-aggregate, 8-deep MLP -------------------------
__global__ __launch_bounds__(256)
void agg_csr(const bf16* __restrict__ P, const int* __restrict__ colptr,
             const int* __restrict__ esrow,
             bf16* __restrict__ aggh, bf16* __restrict__ aggl, int N, int E) {
  const int f = threadIdx.x & 127;
  const int c = blockIdx.x * 2 + (threadIdx.x >> 7);
  if (c >= N) return;
  const int beg = colptr[c];
  const int end = (c == N - 1) ? E : colptr[c + 1];
  float sacc[4] = {0.f, 0.f, 0.f, 0.f};
  int e = beg;
  for (; e + 8 <= end; e += 8) {
    int r[8];
#pragma unroll
    for (int j = 0; j < 8; ++j) r[j] = esrow[e + j];
    float v[8];
#pragma unroll
    for (int j = 0; j < 8; ++j) v[j] = (float)P[(size_t)r[j] * 128 + f];
#pragma unroll
    for (int j = 0; j < 8; ++j) sacc[j & 3] += v[j];
  }
  const int rem = end - e;
  if (rem > 0) {
    int r[8];
#pragma unroll
    for (int j = 0; j < 8; ++j) r[j] = esrow[e + (j < rem ? j : 0)];
#pragma unroll
    for (int j = 0; j < 8; ++j) {
      const float v = (float)P[(size_t)r[j] * 128 + f];
      if (j < rem) sacc[j & 3] += v;
    }
  }
  const int cc = end - beg;
  const float val = ((sacc[0] + sacc[1]) + (sacc[2] + sacc[3])) /
                    (float)(cc > 1 ? cc : 1);
  const bf16 h = (bf16)val;
  aggh[(size_t)c * 128 + f] = h;
  aggl[(size_t)c * 128 + f] = (bf16)(val - (float)h);
}

// ---------------- UW = u @ W1c + b1 (layer 0 only; rest fused in gmlp) ---
__global__ void uw_kernel(const float* __restrict__ u, const float* __restrict__ w1,
                          const float* __restrict__ b1, float* __restrict__ UW) {
  const int b = blockIdx.x, h = threadIdx.x;
  float s = b1[h];
#pragma unroll 8
  for (int k = 0; k < 128; ++k)
    s = fmaf(u[b * 128 + k], w1[(size_t)(256 + k) * 128 + h], s);
  UW[b * 128 + h] = s;
}

// ---------------- node MLP: K=256, acc init UW[batch], fused gsum --------
__global__ __launch_bounds__(256, 4)
void node_mfma(bf16* xh, bf16* xl,
               const bf16* __restrict__ aggh, const bf16* __restrict__ aggl,
               const float* __restrict__ UW, const int* __restrict__ batch,
               const bf16* __restrict__ w1t, const bf16* __restrict__ w2t,
               const float* __restrict__ b2, float* __restrict__ gx,
               float* __restrict__ xout, int write_x, int N) {
  __shared__ __align__(16) bf16 H1[2][64 * 136];   // reused as Xt fp32 [64][132]
  __shared__ int sbatch[64];

  const int tid = threadIdx.x;
  const int n0 = blockIdx.x * 64;
  const int wave = tid >> 6, lane = tid & 63, q = lane >> 4, lr = lane & 15;
  const int hbase = wave * 32;

  if (tid < 64) {
    int n = n0 + tid;
    sbatch[tid] = batch[(n > N - 1) ? (N - 1) : n];
  }

  int nn[4], ub[4];
#pragma unroll
  for (int nt = 0; nt < 4; ++nt) {
    int n = n0 + nt * 16 + lr;
    if (n > N - 1) n = N - 1;
    nn[nt] = n;
    ub[nt] = batch[n];
  }

  floatx4 acc[2][4];
#pragma unroll
  for (int mt = 0; mt < 2; ++mt)
#pragma unroll
    for (int nt = 0; nt < 4; ++nt)
      acc[mt][nt] = *(const floatx4*)&UW[(size_t)ub[nt] * 128 + hbase + mt * 16 + q * 4];

  // GEMM1: K=256 (x hi/lo | agg hi/lo), B double-buffered
  bf16x8 bh[2][4], bl[2][4];
  auto loadB = [&](int kc, int buf) {
#pragma unroll
    for (int nt = 0; nt < 4; ++nt) {
      if (kc < 4) {
        const size_t off = (size_t)nn[nt] * 128 + kc * 32 + q * 8;
        bh[buf][nt] = *(const bf16x8*)(xh + off);
        bl[buf][nt] = *(const bf16x8*)(xl + off);
      } else {
        const size_t off = (size_t)nn[nt] * 128 + (kc - 4) * 32 + q * 8;
        bh[buf][nt] = *(const bf16x8*)(aggh + off);
        bl[buf][nt] = *(const bf16x8*)(aggl + off);
      }
    }
  };
  loadB(0, 0);
#pragma unroll
  for (int kc = 0; kc < 8; ++kc) {
    const int cur = kc & 1, nxt = cur ^ 1;
    if (kc < 7) loadB(kc + 1, nxt);
    bf16x8 ah[2], al[2];
#pragma unroll
    for (int mt = 0; mt < 2; ++mt) {
      const bf16* wp = w1t + (size_t)(hbase + mt * 16 + lr) * 256 + kc * 32 + q * 8;
      ah[mt] = *(const bf16x8*)wp;
      al[mt] = *(const bf16x8*)(wp + 32768);
    }
#pragma unroll
    for (int nt = 0; nt < 4; ++nt)
#pragma unroll
      for (int mt = 0; mt < 2; ++mt) {
        acc[mt][nt] = MFMA(ah[mt], bh[cur][nt], acc[mt][nt], 0, 0, 0);
        acc[mt][nt] = MFMA(al[mt], bh[cur][nt], acc[mt][nt], 0, 0, 0);
        acc[mt][nt] = MFMA(ah[mt], bl[cur][nt], acc[mt][nt], 0, 0, 0);
      }
  }

  // epilogue 1: relu (b1 folded into UW), split -> H1
  const floatx4 zz = {0.f, 0.f, 0.f, 0.f};
#pragma unroll
  for (int mt = 0; mt < 2; ++mt) {
    const int h0 = hbase + mt * 16 + q * 4;
#pragma unroll
    for (int nt = 0; nt < 4; ++nt) {
      const int e = nt * 16 + lr;
      bf16x4 hh, ll;
#pragma unroll
      for (int r = 0; r < 4; ++r) {
        const float v = fmaxf(acc[mt][nt][r], 0.f);
        hh[r] = (bf16)v;
        ll[r] = (bf16)(v - (float)hh[r]);
      }
      *(bf16x4*)&H1[0][e * 136 + h0] = hh;
      *(bf16x4*)&H1[1][e * 136 + h0] = ll;
      acc[mt][nt] = zz;
    }
  }
  __syncthreads();

  // GEMM2
#pragma unroll
  for (int ks = 0; ks < 4; ++ks) {
    bf16x8 ah[2], al[2], b2h[4], b2l[4];
#pragma unroll
    for (int mt = 0; mt < 2; ++mt) {
      const bf16* wp = w2t + (size_t)(hbase + mt * 16 + lr) * 128 + ks * 32 + q * 8;
      ah[mt] = *(const bf16x8*)wp;
      al[mt] = *(const bf16x8*)(wp + 16384);
    }
#pragma unroll
    for (int nt = 0; nt < 4; ++nt) {
      const bf16* hp = &H1[0][(nt * 16 + lr) * 136 + ks * 32 + q * 8];
      b2h[nt] = *(const bf16x8*)hp;
      b2l[nt] = *(const bf16x8*)(hp + 64 * 136);
    }
#pragma unroll
    for (int nt = 0; nt < 4; ++nt)
#pragma unroll
      for (int mt = 0; mt < 2; ++mt) {
        acc[mt][nt] = MFMA(ah[mt], b2h[nt], acc[mt][nt], 0, 0, 0);
        acc[mt][nt] = MFMA(al[mt], b2h[nt], acc[mt][nt], 0, 0, 0);
        acc[mt][nt] = MFMA(ah[mt], b2l[nt], acc[mt][nt], 0, 0, 0);
      }
  }
  __syncthreads();   // all H1 reads done; Xt fp32 [64][132] overlays H1

  // epilogue 2: +b2 -> Xt row-major tile (float4 per fragment)
  float* Xt = (float*)&H1[0][0];
#pragma unroll
  for (int mt = 0; mt < 2; ++mt) {
    const int f0 = hbase + mt * 16 + q * 4;
    const float* bp = &b2[f0];
#pragma unroll
    for (int nt = 0; nt < 4; ++nt) {
      const int e = nt * 16 + lr;
      const int n = n0 + e;
      float4 o;
      o.x = (n < N) ? acc[mt][nt][0] + bp[0] : 0.f;
      o.y = (n < N) ? acc[mt][nt][1] + bp[1] : 0.f;
      o.z = (n < N) ? acc[mt][nt][2] + bp[2] : 0.f;
      o.w = (n < N) ? acc[mt][nt][3] + bp[3] : 0.f;
      *(float4*)&Xt[e * 132 + f0] = o;
    }
  }
  __syncthreads();

  // coalesced stores: xh/xl (bf16x8/lane, consecutive lanes contiguous)
#pragma unroll
  for (int it = 0; it < 4; ++it) {
    const int idx = it * 256 + tid;
    const int row = idx >> 4;
    const int f8 = (idx & 15) * 8;
    const int n = n0 + row;
    if (n < N) {
      bf16x8 hh, ll;
#pragma unroll
      for (int j = 0; j < 8; ++j) {
        const float v = Xt[row * 132 + f8 + j];
        hh[j] = (bf16)v;
        ll[j] = (bf16)(v - (float)hh[j]);
      }
      *(bf16x8*)&xh[(size_t)n * 128 + f8] = hh;
      *(bf16x8*)&xl[(size_t)n * 128 + f8] = ll;
    }
  }
  if (write_x) {
#pragma unroll
    for (int it = 0; it < 8; ++it) {
      const int idx = it * 256 + tid;
      const int row = idx >> 5;
      const int f4 = (idx & 31) * 4;
      const int n = n0 + row;
      if (n < N)
        *(float4*)&xout[(size_t)n * 128 + f4] = *(const float4*)&Xt[row * 132 + f4];
    }
  }

  // fused gsum: segmented reduce over 64 sorted-batch nodes, ~1 atomic/f
  {
    const int f = tid & 127;
    const int es = (tid >> 7) * 32;
    int cur = sbatch[es];
    float s = 0.f;
    for (int e = es; e < es + 32; ++e) {
      const int b = sbatch[e];
      const float v = Xt[e * 132 + f];
      if (b != cur) {
        atomicAdd(&gx[(size_t)cur * 128 + f], s);
        s = 0.f;
        cur = b;
      }
      s += v;
    }
    atomicAdd(&gx[(size_t)cur * 128 + f], s);
  }
}

// ---------------- global MLP + fused UW for next layer -------------------
__global__ __launch_bounds__(128)
void gmlp_kernel(const float* __restrict__ uin, float* __restrict__ gx,
                 const int* __restrict__ gcnt,
                 const float* __restrict__ gw1, const float* __restrict__ gb1,
                 const float* __restrict__ gw2, const float* __restrict__ gb2,
                 float* __restrict__ uout,
                 const float* __restrict__ w1n_next,
                 const float* __restrict__ b1n_next,
                 float* __restrict__ UW, int has_next) {
  __shared__ float g[256];
  __shared__ float g1[128];
  const int b = blockIdx.x;
  const int t = threadIdx.x;
  const int c = gcnt[b];
  const float inv = 1.f / (float)(c > 1 ? c : 1);
  g[t] = uin[b * 128 + t];
  g[128 + t] = gx[b * 128 + t] * inv;
  gx[b * 128 + t] = 0.f;
  __syncthreads();
  float acc = gb1[t];
#pragma unroll 8
  for (int k = 0; k < 256; ++k) acc = fmaf(g[k], gw1[k * 128 + t], acc);
  g1[t] = fmaxf(acc, 0.f);
  __syncthreads();
  float acc2 = gb2[t];
#pragma unroll 8
  for (int k = 0; k < 128; ++k) acc2 = fmaf(g1[k], gw2[k * 128 + t], acc2);
  uout[b * 128 + t] = acc2;
  if (has_next) {   // UW[b] = uout[b] @ W1c_{l+1} + b1_{l+1}
    __syncthreads();
    g[t] = acc2;
    __syncthreads();
    float s = b1n_next[t];
#pragma unroll 8
    for (int k = 0; k < 128; ++k)
      s = fmaf(g[k], w1n_next[(size_t)(256 + k) * 128 + t], s);
    UW[b * 128 + t] = s;
  }
}

// ---------------- host ----------------
extern "C" void kernel_launch(void* const* d_in, const int* in_sizes, int n_in,
                              void* d_out, int out_size, void* d_ws, size_t ws_size,
                              hipStream_t stream) {
  constexpr int N = 50000, E = 600000, B = 64, F = 128, L = 4;

  const float* x0    = (const float*)d_in[0];
  const int*   ei    = (const int*)  d_in[1];
  const float* u0    = (const float*)d_in[2];
  const int*   batch = (const int*)  d_in[3];
  const float* n1w1  = (const float*)d_in[4];
  const float* n1b1  = (const float*)d_in[5];
  const float* n1w2  = (const float*)d_in[6];
  const float* n1b2  = (const float*)d_in[7];
  const float* n2w1  = (const float*)d_in[8];
  const float* n2b1  = (const float*)d_in[9];
  const float* n2w2  = (const float*)d_in[10];
  const float* n2b2  = (const float*)d_in[11];
  const float* gw1   = (const float*)d_in[12];
  const float* gb1   = (const float*)d_in[13];
  const float* gw2   = (const float*)d_in[14];
  const float* gb2   = (const float*)d_in[15];
  float* out = (float*)d_out;

  char* p = (char*)d_ws;
  auto carve = [&](size_t bytes) -> void* {
    void* q = (void*)p;
    p += (bytes + 255) & ~(size_t)255;
    return q;
  };
  float* ubuf  = (float*)carve((size_t)B * F * 4);
  float* gx    = (float*)carve((size_t)B * F * 4);
  float* UW    = (float*)carve((size_t)B * F * 4);
  int*   cnt   = (int*)carve((size_t)N * 4);
  int*   colptr= (int*)carve((size_t)(N + 1) * 4);
  int*   rctr  = (int*)carve((size_t)N * 4);
  int*   gcnt  = (int*)carve((size_t)B * 4);
  int*   btot  = (int*)carve(32 * 4);
  int*   esrow = (int*)carve((size_t)E * 4);
  bf16*  xhi   = (bf16*)carve((size_t)N * F * 2);
  bf16*  xlo   = (bf16*)carve((size_t)N * F * 2);
  bf16*  P     = (bf16*)carve((size_t)N * F * 2);
  bf16*  aggh  = (bf16*)carve((size_t)N * F * 2);
  bf16*  aggl  = (bf16*)carve((size_t)N * F * 2);
  bf16*  w1t_e = (bf16*)carve((size_t)L * 2 * 128 * 128 * 2);
  bf16*  w2t_e = (bf16*)carve((size_t)L * 2 * 128 * 128 * 2);
  bf16*  w1t_n = (bf16*)carve((size_t)L * 2 * 256 * 128 * 2);
  bf16*  w2t_n = (bf16*)carve((size_t)L * 2 * 128 * 128 * 2);

  constexpr int SCAN_BLOCKS = (N + 2047) / 2048;

  hipMemsetAsync(cnt, 0, (size_t)N * 4, stream);
  hipMemsetAsync(gx, 0, (size_t)B * F * 4, stream);   // re-zeroed by gmlp
  hist_kernel<<<(E + 255) / 256, 256, 0, stream>>>(ei, cnt, E);
  gcnt_kernel<<<1, 64, 0, stream>>>(batch, gcnt, N, B);
  scan1_kernel<<<SCAN_BLOCKS, 256, 0, stream>>>(cnt, colptr, rctr, btot, N);
  scan2_kernel<<<SCAN_BLOCKS, 256, 0, stream>>>(colptr, rctr, btot, N);
  place_kernel<<<(E + 255) / 256, 256, 0, stream>>>(ei, rctr, esrow, E);
  wsplit_kernel<<<dim3(64, L), 256, 0, stream>>>(n1w1, w1t_e, 128, 128, 128);
  wsplit_kernel<<<dim3(64, L), 256, 0, stream>>>(n1w2, w2t_e, 128, 128, 128);
  wsplit_kernel<<<dim3(128, L), 256, 0, stream>>>(n2w1, w1t_n, 384, 256, 128);
  wsplit_kernel<<<dim3(64, L), 256, 0, stream>>>(n2w2, w2t_n, 128, 128, 128);
  xsplit_kernel<<<(N * F / 4 + 255) / 256, 256, 0, stream>>>(x0, xhi, xlo, N * F / 4);
  uw_kernel<<<B, 128, 0, stream>>>(u0, n2w1, n2b1, UW);   // layer-0 UW

  const int NB = (N + 63) / 64;
  for (int l = 0; l < L; ++l) {
    const float* uin  = l ? ubuf : u0;
    float*       uout = (l == L - 1) ? out + (size_t)N * F : ubuf;
    const int    wx   = (l == L - 1) ? 1 : 0;
    const int    hn   = (l < L - 1) ? 1 : 0;

    pnode_mfma<<<NB, 256, 0, stream>>>(
        xhi, xlo,
        w1t_e + (size_t)l * 32768, n1b1 + l * 128,
        w2t_e + (size_t)l * 32768, n1b2 + l * 128, P, N);
    agg_csr<<<(N + 1) / 2, 256, 0, stream>>>(P, colptr, esrow, aggh, aggl, N, E);
    node_mfma<<<NB, 256, 0, stream>>>(
        xhi, xlo, aggh, aggl, UW, batch,
        w1t_n + (size_t)l * 65536, w2t_n + (size_t)l * 32768,
        n2b2 + l * 128, gx, out, wx, N);
    gmlp_kernel<<<B, 128, 0, stream>>>(
        uin, gx, gcnt,
        gw1 + (size_t)l * 256 * 128, gb1 + l * 128,
        gw2 + (size_t)l * 128 * 128, gb2 + l * 128, uout,
        hn ? (n2w1 + (size_t)(l + 1) * 384 * 128) : n2w1,
        hn ? (n2b1 + (l + 1) * 128) : n2b1,
        UW, hn);
  }
}